// Round 3
// baseline (2805.107 us; speedup 1.0000x reference)
//
#include <hip/hip_runtime.h>
#include <cstdint>

static constexpr int B   = 8;
static constexpr int N0  = 4096;
static constexpr int NQ  = 1024;
static constexpr int KNB = 16;

// ---------------------------------------------------------------------------
// DPP wave reductions (no DS ops). Classic GCN sequence:
// row_shr 1,2,4,8 then row_bcast15, row_bcast31; full-wave result in lane 63.
// update_dpp(old=x, src=x, ...) -> invalid lanes keep x (identity element).
// ---------------------------------------------------------------------------
__device__ __forceinline__ float wave_max_bcast_f32(float x) {
#define STEP_(ctrl)                                                                     \
  {                                                                                     \
    int t_ = __builtin_amdgcn_update_dpp(__float_as_int(x), __float_as_int(x), ctrl,    \
                                         0xf, 0xf, false);                              \
    x = fmaxf(x, __int_as_float(t_));                                                   \
  }
  STEP_(0x111) STEP_(0x112) STEP_(0x114) STEP_(0x118) STEP_(0x142) STEP_(0x143)
#undef STEP_
  return __int_as_float(__builtin_amdgcn_readlane(__float_as_int(x), 63));
}

__device__ __forceinline__ float wave_min_bcast_f32(float x) {
#define STEP_(ctrl)                                                                     \
  {                                                                                     \
    int t_ = __builtin_amdgcn_update_dpp(__float_as_int(x), __float_as_int(x), ctrl,    \
                                         0xf, 0xf, false);                              \
    x = fminf(x, __int_as_float(t_));                                                   \
  }
  STEP_(0x111) STEP_(0x112) STEP_(0x114) STEP_(0x118) STEP_(0x142) STEP_(0x143)
#undef STEP_
  return __int_as_float(__builtin_amdgcn_readlane(__float_as_int(x), 63));
}

__device__ __forceinline__ unsigned wave_min_bcast_u32(unsigned x) {
#define STEP_(ctrl)                                                                     \
  {                                                                                     \
    unsigned t_ = (unsigned)__builtin_amdgcn_update_dpp((int)x, (int)x, ctrl,           \
                                                        0xf, 0xf, false);               \
    x = (t_ < x) ? t_ : x;                                                              \
  }
  STEP_(0x111) STEP_(0x112) STEP_(0x114) STEP_(0x118) STEP_(0x142) STEP_(0x143)
#undef STEP_
  return (unsigned)__builtin_amdgcn_readlane((int)x, 63);
}

// ---------------------------------------------------------------------------
// prep: split x; write packed c4 = {x,y,z,|c|^2}, normal, plane, f0
// ---------------------------------------------------------------------------
__global__ void prep_kernel(const float* __restrict__ x,
                            const float* __restrict__ W_in,
                            const float* __restrict__ b_in,
                            float4* __restrict__ c4, float* __restrict__ nrm,
                            float* __restrict__ pl, float* __restrict__ f0) {
  int i = blockIdx.x * 256 + threadIdx.x;
  if (i >= B * N0) return;
  const float* xp = x + (size_t)i * 7;
  float cx = xp[0], cy = xp[1], cz = xp[2];
  // tie-sensitive (feeds kNN distance): exact fp32, ref association order
  float kk = __fadd_rn(__fadd_rn(__fmul_rn(cx, cx), __fmul_rn(cy, cy)), __fmul_rn(cz, cz));
  c4[i] = make_float4(cx, cy, cz, kk);
  nrm[i * 3 + 0] = xp[3]; nrm[i * 3 + 1] = xp[4]; nrm[i * 3 + 2] = xp[5];
  pl[i] = xp[6];
#pragma unroll
  for (int o = 0; o < 8; o++) {
    f0[(size_t)i * 8 + o] = cx * W_in[o * 3 + 0] + cy * W_in[o * 3 + 1] + cz * W_in[o * 3 + 2] + b_in[o];
  }
}

// ---------------------------------------------------------------------------
// kNN: wave per query. Lane owns M=Nk/64 candidates (one dwordx4 load each).
// 16 rounds of DPP wave argmin (tie -> smaller index, matches stable top_k).
// d2 = ((|q|^2 - 2*dot) + |k|^2), exact fp32 non-fused like the reference.
// ---------------------------------------------------------------------------
template <int M>
__global__ void knn_kernel(const float4* __restrict__ q4, const float4* __restrict__ k4,
                           int Q, int Nk, int* __restrict__ out) {
  int gt = blockIdx.x * 256 + threadIdx.x;
  int bq = gt >> 6;
  int lane = gt & 63;
  int b = bq / Q;
  float4 q = q4[bq];
  const float4* kb = k4 + (size_t)b * Nk;
  float d[M];
#pragma unroll
  for (int i = 0; i < M; i++) {
    float4 kp = kb[i * 64 + lane];
    float dot = __fadd_rn(__fadd_rn(__fmul_rn(q.x, kp.x), __fmul_rn(q.y, kp.y)),
                          __fmul_rn(q.z, kp.z));
    d[i] = __fadd_rn(__fsub_rn(q.w, __fmul_rn(2.0f, dot)), kp.w);
  }
  unsigned long long mask = 0ull;
  float lv = 3.0e38f; int li = 0;
#pragma unroll
  for (int i = 0; i < M; i++) { if (d[i] < lv) { lv = d[i]; li = i; } }
  int mynb = 0;
  for (int r = 0; r < KNB; r++) {
    int n = li * 64 + lane;
    float wmin = wave_min_bcast_f32(lv);
    unsigned ci = (lv == wmin) ? (unsigned)n : 0xFFFFFFFFu;
    int wn = (int)wave_min_bcast_u32(ci);
    if (lane == r) mynb = wn;
    if (lane == (wn & 63)) {  // this lane owned the winner: mark + rescan
      mask |= 1ull << (wn >> 6);
      lv = 3.0e38f; li = 0;
#pragma unroll
      for (int i = 0; i < M; i++) {
        bool dead = (mask >> i) & 1ull;
        float dv = dead ? 3.0e38f : d[i];
        if (dv < lv) { lv = dv; li = i; }
      }
    }
  }
  if (lane < KNB) out[(size_t)bq * KNB + lane] = mynb;
}

// ---------------------------------------------------------------------------
// ctrY[b,q,o] = sum_c fq[b,q,c] * W[o, CF+c]   (K-independent half of conv)
// ---------------------------------------------------------------------------
template <int CF, int CO>
__global__ void ctry_kernel(const float* __restrict__ fq, const float* __restrict__ W,
                            float* __restrict__ ctrY, int total) {
  int i = blockIdx.x * 256 + threadIdx.x;
  if (i >= total) return;
  int o = i % CO, bq = i / CO;
  const float* fp = fq + (size_t)bq * CF;
  const float* wp = W + (size_t)o * (2 * CF) + CF;
  float acc = 0.f;
#pragma unroll
  for (int c = 0; c < CF; c++) acc = fmaf(fp[c], wp[c], acc);
  ctrY[i] = acc;
}

// ---------------------------------------------------------------------------
// edge-conv pass A: wave per (b,q); lane = g*16+k (g: o-chunk==GN group, k: nbr)
// y = Wl*(nb-ctr) + ctrY; min/max over k per channel; per-(b,group) sum/sumsq.
// ---------------------------------------------------------------------------
template <int CF, int CO>
__global__ __launch_bounds__(256) void edgeconv_kernel(
    const float* __restrict__ fq, const float* __restrict__ fk,
    const int* __restrict__ knn, const float* __restrict__ Wfull,
    const float* __restrict__ ctrY,
    float* __restrict__ ymin, float* __restrict__ ymax,
    float* __restrict__ gstats, int Q, int Nk) {
  constexpr int J = CO / 4;
  constexpr int SEC = J * CF + 8;
  __shared__ float Wl[4 * SEC];
  __shared__ float sstat[8];
  for (int t = threadIdx.x; t < CO * CF; t += 256) {
    int o = t / CF, c = t % CF;
    Wl[(o / J) * SEC + (o % J) * CF + c] = Wfull[(size_t)o * (2 * CF) + c];
  }
  if (threadIdx.x < 8) sstat[threadIdx.x] = 0.0f;
  __syncthreads();
  const int wid = threadIdx.x >> 6, lane = threadIdx.x & 63;
  const int bq = blockIdx.x * 4 + wid;
  const int b = bq / Q;
  const int g = lane >> 4, k = lane & 15;
  const int ni = knn[(size_t)bq * KNB + k];
  const float* nbp = fk + (size_t)(b * Nk + ni) * CF;
  const float* cp  = fq + (size_t)bq * CF;
  float acc[J];
#pragma unroll
  for (int j = 0; j < J; j++) acc[j] = 0.0f;
  const float* wg = &Wl[g * SEC];
#pragma unroll
  for (int c = 0; c < CF; c += 4) {
    float4 nb4 = *(const float4*)(nbp + c);
    float4 c4  = *(const float4*)(cp + c);
    float e0 = nb4.x - c4.x, e1 = nb4.y - c4.y, e2 = nb4.z - c4.z, e3 = nb4.w - c4.w;
#pragma unroll
    for (int j = 0; j < J; j++) {
      float4 w4 = *(const float4*)(wg + j * CF + c);
      acc[j] = fmaf(e0, w4.x, acc[j]);
      acc[j] = fmaf(e1, w4.y, acc[j]);
      acc[j] = fmaf(e2, w4.z, acc[j]);
      acc[j] = fmaf(e3, w4.w, acc[j]);
    }
  }
  float s = 0.f, s2 = 0.f;
  const float* cyp = ctrY + (size_t)bq * CO + g * J;
#pragma unroll
  for (int j = 0; j < J; j++) {
    float y = acc[j] + cyp[j];
    acc[j] = y;            // acc becomes running max
    s += y; s2 = fmaf(y, y, s2);
  }
  float mn[J];
#pragma unroll
  for (int j = 0; j < J; j++) mn[j] = acc[j];
#pragma unroll
  for (int m = 1; m < 16; m <<= 1) {  // reduce over the 16 k-lanes
#pragma unroll
    for (int j = 0; j < J; j++) {
      float a = __shfl_xor(acc[j], m); if (a > acc[j]) acc[j] = a;
      float c2 = __shfl_xor(mn[j], m); if (c2 < mn[j]) mn[j] = c2;
    }
    s  += __shfl_xor(s, m);
    s2 += __shfl_xor(s2, m);
  }
  if (k == 0) {
    float* mnp = ymin + (size_t)bq * CO + g * J;
    float* mxp = ymax + (size_t)bq * CO + g * J;
#pragma unroll
    for (int j = 0; j < J; j++) { mnp[j] = mn[j]; mxp[j] = acc[j]; }
    atomicAdd(&sstat[g], s);
    atomicAdd(&sstat[4 + g], s2);
  }
  __syncthreads();
  if (threadIdx.x < 8) atomicAdd(&gstats[b * 8 + threadIdx.x], sstat[threadIdx.x]);
}

// ---------------------------------------------------------------------------
// pass B (gn_final fused): m/rs computed per-thread from gstats;
// f = lrelu((sel - m)*gw*rs + gb), sel = max if scale>=0 else min.
// ---------------------------------------------------------------------------
template <int CO>
__global__ void gn_out_kernel(const float* __restrict__ ymin, const float* __restrict__ ymax,
                              const float* __restrict__ gstats, const float* __restrict__ gw,
                              const float* __restrict__ gb, float* __restrict__ fout,
                              int total, int Q, float inv_cnt) {
  int i = blockIdx.x * 256 + threadIdx.x;
  if (i >= total) return;
  constexpr int J = CO / 4;
  int o = i % CO; int bq = i / CO; int b = bq / Q;
  int g = o / J;
  float m  = gstats[b * 8 + g] * inv_cnt;
  float s2 = gstats[b * 8 + 4 + g] * inv_cnt;
  float rs = rsqrtf(s2 - m * m + 1e-5f);
  float sc = gw[o] * rs;
  float sel = (sc >= 0.f) ? ymax[i] : ymin[i];
  float v = (sel - m) * sc + gb[o];
  fout[i] = (v > 0.f) ? v : 0.2f * v;
}

// ---------------------------------------------------------------------------
// FPS v3: block per batch, BLK=256. Coords in registers; DPP wave argmax
// (value max then min-index among equals — exact jnp.argmax tie semantics);
// winner lane posts {key, coords} to its wave slot; one barrier/iter with
// ping-pong slots; all lanes redundantly reduce the 4 slots (keys + coords
// read concurrently, selected by cndmask — no indexed LDS read in the chain).
// ---------------------------------------------------------------------------
template <int NPTS, int BLK>
__global__ __launch_bounds__(BLK) void fps_kernel(const float4* __restrict__ c4,
                                                  int* __restrict__ idx_out, int num) {
  constexpr int M = NPTS / BLK;
  constexpr int NW = BLK / 64;
  __shared__ unsigned long long skey[2][NW];
  __shared__ float4 scoord[2][NW];
  const int b = blockIdx.x, tid = threadIdx.x;
  const int wid = tid >> 6, lane = tid & 63;
  const float4* cb = c4 + (size_t)b * NPTS;
  float cx[M], cy[M], cz[M], dist[M];
#pragma unroll
  for (int i = 0; i < M; i++) {
    float4 p = cb[tid + i * BLK];
    cx[i] = p.x; cy[i] = p.y; cz[i] = p.z;
    dist[i] = 3.4e38f;
  }
  if (tid == 0) idx_out[(size_t)b * num] = 0;
  float4 p0 = cb[0];
  float px = p0.x, py = p0.y, pz = p0.z;
  for (int t = 1; t < num; t++) {
    float bv = -1.f; int bi = 0;
    float bcx = 0.f, bcy = 0.f, bcz = 0.f;
#pragma unroll
    for (int i = 0; i < M; i++) {
      float dx = __fsub_rn(cx[i], px), dy = __fsub_rn(cy[i], py), dz = __fsub_rn(cz[i], pz);
      float d = __fadd_rn(__fadd_rn(__fmul_rn(dx, dx), __fmul_rn(dy, dy)), __fmul_rn(dz, dz));
      float dd = dist[i]; dd = (d < dd) ? d : dd; dist[i] = dd;
      if (dd > bv) { bv = dd; bi = tid + i * BLK; bcx = cx[i]; bcy = cy[i]; bcz = cz[i]; }
    }
    // intra-wave argmax: max value, then min index among value-equal lanes
    float wv = wave_max_bcast_f32(bv);
    unsigned ci = (bv == wv) ? (unsigned)bi : 0xFFFFFFFFu;
    int wi = (int)wave_min_bcast_u32(ci);
    int p = t & 1;
    if (lane == (wi & 63)) {  // unique owner lane (BLK % 64 == 0 -> wi&63 == lane)
      skey[p][wid] = ((unsigned long long)__float_as_uint(wv) << 12) | (unsigned)(4095 - wi);
      scoord[p][wid] = make_float4(bcx, bcy, bcz, 0.f);
    }
    __syncthreads();
    unsigned long long bestk = skey[p][0];
    float4 bc = scoord[p][0];
#pragma unroll
    for (int w = 1; w < NW; w++) {
      unsigned long long k2 = skey[p][w];
      float4 c2 = scoord[p][w];
      if (k2 > bestk) { bestk = k2; bc = c2; }
    }
    px = bc.x; py = bc.y; pz = bc.z;
    if (tid == 0) idx_out[(size_t)b * num + t] = 4095 - (int)(bestk & 0xFFFull);
  }
}

// ---------------------------------------------------------------------------
// gather at FPS indices: packed c4, (optional) 3-packed coords, normal, plane, f
// ---------------------------------------------------------------------------
template <int CF>
__global__ void gather_kernel(const int* __restrict__ idx,
                              const float4* __restrict__ c4s, const float* __restrict__ nrms,
                              const float* __restrict__ pls, const float* __restrict__ fs,
                              float4* __restrict__ c4d, float* __restrict__ cd3,
                              float* __restrict__ nd, float* __restrict__ pd,
                              float* __restrict__ fd, int Nsrc, int num) {
  int i = blockIdx.x * 256 + threadIdx.x;
  if (i >= B * num) return;
  int b = i / num;
  int src = b * Nsrc + idx[i];
  float4 c = c4s[src];
  c4d[i] = c;
  cd3[i * 3 + 0] = c.x; cd3[i * 3 + 1] = c.y; cd3[i * 3 + 2] = c.z;
  nd[i * 3 + 0] = nrms[(size_t)src * 3 + 0];
  nd[i * 3 + 1] = nrms[(size_t)src * 3 + 1];
  nd[i * 3 + 2] = nrms[(size_t)src * 3 + 2];
  pd[i] = pls[src];
#pragma unroll 4
  for (int c2 = 0; c2 < CF; c2++) fd[(size_t)i * CF + c2] = fs[(size_t)src * CF + c2];
}

// ---------------------------------------------------------------------------
extern "C" void kernel_launch(void* const* d_in, const int* in_sizes, int n_in,
                              void* d_out, int out_size, void* d_ws, size_t ws_size,
                              hipStream_t stream) {
  (void)in_sizes; (void)n_in; (void)out_size; (void)ws_size;
  const float* x    = (const float*)d_in[0];
  const float* W_in = (const float*)d_in[1];
  const float* b_in = (const float*)d_in[2];
  const float* W1   = (const float*)d_in[3];
  const float* g1w  = (const float*)d_in[4];
  const float* g1b  = (const float*)d_in[5];
  const float* W2   = (const float*)d_in[6];
  const float* g2w  = (const float*)d_in[7];
  const float* g2b  = (const float*)d_in[8];
  const float* W3   = (const float*)d_in[9];
  const float* g3w  = (const float*)d_in[10];
  const float* g3b  = (const float*)d_in[11];
  const float* W4   = (const float*)d_in[12];
  const float* g4w  = (const float*)d_in[13];
  const float* g4b  = (const float*)d_in[14];

  float* ws = (float*)d_ws;
  size_t o_c40  = 0;                                         // float4-aligned (ws base)
  size_t o_nrm  = o_c40  + (size_t)B * N0 * 4;
  size_t o_pl   = o_nrm  + (size_t)B * N0 * 3;
  size_t o_f0   = o_pl   + (size_t)B * N0;
  size_t o_f1   = o_f0   + (size_t)B * N0 * 8;
  size_t o_ctrY = o_f1   + (size_t)B * N0 * 32;
  size_t o_ymin = o_ctrY + (size_t)B * N0 * 32;
  size_t o_ymax = o_ymin + (size_t)B * N0 * 32;
  size_t o_knn  = o_ymax + (size_t)B * N0 * 32;              // int region
  size_t o_gst  = o_knn  + (size_t)B * N0 * KNB;
  size_t o_idx1 = o_gst  + 4 * B * 8;                        // int region
  size_t o_idx2 = o_idx1 + (size_t)B * NQ;                   // int region
  size_t o_c4q1 = o_idx2 + (size_t)B * NQ;                   // float4-aligned
  size_t o_nq1  = o_c4q1 + (size_t)B * NQ * 4;
  size_t o_pq1  = o_nq1  + (size_t)B * NQ * 3;
  size_t o_fq1  = o_pq1  + (size_t)B * NQ;
  size_t o_f2   = o_fq1  + (size_t)B * NQ * 32;
  size_t o_f3   = o_f2   + (size_t)B * NQ * 64;
  size_t o_c4q2 = o_f3   + (size_t)B * NQ * 64;              // float4-aligned
  size_t o_fq2  = o_c4q2 + (size_t)B * NQ * 4;
  size_t o_dmp3 = o_fq2  + (size_t)B * NQ * 64;              // dummy 3-packed coords

  float4* c40  = (float4*)(ws + o_c40);
  float*  nrm  = ws + o_nrm;   float* pl   = ws + o_pl;
  float*  f0   = ws + o_f0;    float* f1   = ws + o_f1;
  float*  ctrY = ws + o_ctrY;  float* ymin = ws + o_ymin;  float* ymax = ws + o_ymax;
  int*    knn  = (int*)(ws + o_knn);
  float*  gst  = ws + o_gst;
  int*    idx1 = (int*)(ws + o_idx1);
  int*    idx2 = (int*)(ws + o_idx2);
  float4* c4q1 = (float4*)(ws + o_c4q1);
  float*  nq1  = ws + o_nq1;   float* pq1  = ws + o_pq1;   float* fq1 = ws + o_fq1;
  float*  f2   = ws + o_f2;    float* f3   = ws + o_f3;
  float4* c4q2 = (float4*)(ws + o_c4q2);
  float*  fq2  = ws + o_fq2;
  float*  dmp3 = ws + o_dmp3;

  float* out  = (float*)d_out;
  float* cq2  = out;                                   // (B,NQ,3)
  float* fout = out + (size_t)B * NQ * 3;              // (B,NQ,128)
  float* nq2  = fout + (size_t)B * NQ * 128;           // (B,NQ,3)
  float* pq2  = nq2 + (size_t)B * NQ * 3;              // (B,NQ,1)

  hipMemsetAsync(gst, 0, 4 * B * 8 * sizeof(float), stream);

  // stage 0
  prep_kernel<<<(B * N0 + 255) / 256, 256, 0, stream>>>(x, W_in, b_in, c40, nrm, pl, f0);

  // ---- layer 1: Q=4096, keys=4096, CF=8, CO=32 ----
  ctry_kernel<8, 32><<<(B * N0 * 32 + 255) / 256, 256, 0, stream>>>(f0, W1, ctrY, B * N0 * 32);
  knn_kernel<64><<<B * N0 * 64 / 256, 256, 0, stream>>>(c40, c40, N0, N0, knn);
  edgeconv_kernel<8, 32><<<B * N0 / 4, 256, 0, stream>>>(f0, f0, knn, W1, ctrY, ymin, ymax, gst + 0, N0, N0);
  gn_out_kernel<32><<<(B * N0 * 32 + 255) / 256, 256, 0, stream>>>(ymin, ymax, gst + 0, g1w, g1b, f1, B * N0 * 32, N0, 1.0f / (4096.0f * 16.0f * 8.0f));

  // FPS 1 + gather
  fps_kernel<4096, 256><<<B, 256, 0, stream>>>(c40, idx1, NQ);
  gather_kernel<32><<<(B * NQ + 255) / 256, 256, 0, stream>>>(idx1, c40, nrm, pl, f1,
                                                              c4q1, dmp3, nq1, pq1, fq1, N0, NQ);

  // ---- layer 2: Q=1024, keys=4096, CF=32, CO=64 ----
  ctry_kernel<32, 64><<<(B * NQ * 64 + 255) / 256, 256, 0, stream>>>(fq1, W2, ctrY, B * NQ * 64);
  knn_kernel<64><<<B * NQ * 64 / 256, 256, 0, stream>>>(c4q1, c40, NQ, N0, knn);
  edgeconv_kernel<32, 64><<<B * NQ / 4, 256, 0, stream>>>(fq1, f1, knn, W2, ctrY, ymin, ymax, gst + B * 8, NQ, N0);
  gn_out_kernel<64><<<(B * NQ * 64 + 255) / 256, 256, 0, stream>>>(ymin, ymax, gst + B * 8, g2w, g2b, f2, B * NQ * 64, NQ, 1.0f / (1024.0f * 16.0f * 16.0f));

  // ---- layer 3: Q=1024, keys=1024, CF=64, CO=64 ----
  ctry_kernel<64, 64><<<(B * NQ * 64 + 255) / 256, 256, 0, stream>>>(f2, W3, ctrY, B * NQ * 64);
  knn_kernel<16><<<B * NQ * 64 / 256, 256, 0, stream>>>(c4q1, c4q1, NQ, NQ, knn);
  edgeconv_kernel<64, 64><<<B * NQ / 4, 256, 0, stream>>>(f2, f2, knn, W3, ctrY, ymin, ymax, gst + 2 * B * 8, NQ, NQ);
  gn_out_kernel<64><<<(B * NQ * 64 + 255) / 256, 256, 0, stream>>>(ymin, ymax, gst + 2 * B * 8, g3w, g3b, f3, B * NQ * 64, NQ, 1.0f / (1024.0f * 16.0f * 16.0f));

  // FPS 2 + gather (coor_q/normal_q/plane_q go straight to d_out)
  fps_kernel<1024, 256><<<B, 256, 0, stream>>>(c4q1, idx2, NQ);
  gather_kernel<64><<<(B * NQ + 255) / 256, 256, 0, stream>>>(idx2, c4q1, nq1, pq1, f3,
                                                              c4q2, cq2, nq2, pq2, fq2, NQ, NQ);

  // ---- layer 4: Q=1024, keys=1024, CF=64, CO=128 ----
  ctry_kernel<64, 128><<<(B * NQ * 128 + 255) / 256, 256, 0, stream>>>(fq2, W4, ctrY, B * NQ * 128);
  knn_kernel<16><<<B * NQ * 64 / 256, 256, 0, stream>>>(c4q2, c4q1, NQ, NQ, knn);
  edgeconv_kernel<64, 128><<<B * NQ / 4, 256, 0, stream>>>(fq2, f3, knn, W4, ctrY, ymin, ymax, gst + 3 * B * 8, NQ, NQ);
  gn_out_kernel<128><<<(B * NQ * 128 + 255) / 256, 256, 0, stream>>>(ymin, ymax, gst + 3 * B * 8, g4w, g4b, fout, B * NQ * 128, NQ, 1.0f / (1024.0f * 16.0f * 32.0f));
}

// Round 4
// 2506.550 us; speedup vs baseline: 1.1191x; 1.1191x over previous
//
#include <hip/hip_runtime.h>
#include <cstdint>

static constexpr int B   = 8;
static constexpr int N0  = 4096;
static constexpr int NQ  = 1024;
static constexpr int KNB = 16;

// ---------------------------------------------------------------------------
// DPP wave reductions (no DS ops). row_shr 1,2,4,8 + row_bcast15/31;
// full-wave result in lane 63. update_dpp(old=x, src=x): invalid lanes keep x.
// ---------------------------------------------------------------------------
__device__ __forceinline__ float wave_max_bcast_f32(float x) {
#define STEP_(ctrl)                                                                     \
  {                                                                                     \
    int t_ = __builtin_amdgcn_update_dpp(__float_as_int(x), __float_as_int(x), ctrl,    \
                                         0xf, 0xf, false);                              \
    x = fmaxf(x, __int_as_float(t_));                                                   \
  }
  STEP_(0x111) STEP_(0x112) STEP_(0x114) STEP_(0x118) STEP_(0x142) STEP_(0x143)
#undef STEP_
  return __int_as_float(__builtin_amdgcn_readlane(__float_as_int(x), 63));
}

__device__ __forceinline__ float wave_min_bcast_f32(float x) {
#define STEP_(ctrl)                                                                     \
  {                                                                                     \
    int t_ = __builtin_amdgcn_update_dpp(__float_as_int(x), __float_as_int(x), ctrl,    \
                                         0xf, 0xf, false);                              \
    x = fminf(x, __int_as_float(t_));                                                   \
  }
  STEP_(0x111) STEP_(0x112) STEP_(0x114) STEP_(0x118) STEP_(0x142) STEP_(0x143)
#undef STEP_
  return __int_as_float(__builtin_amdgcn_readlane(__float_as_int(x), 63));
}

__device__ __forceinline__ unsigned wave_min_bcast_u32(unsigned x) {
#define STEP_(ctrl)                                                                     \
  {                                                                                     \
    unsigned t_ = (unsigned)__builtin_amdgcn_update_dpp((int)x, (int)x, ctrl,           \
                                                        0xf, 0xf, false);               \
    x = (t_ < x) ? t_ : x;                                                              \
  }
  STEP_(0x111) STEP_(0x112) STEP_(0x114) STEP_(0x118) STEP_(0x142) STEP_(0x143)
#undef STEP_
  return (unsigned)__builtin_amdgcn_readlane((int)x, 63);
}

// Row-confined u64 max over the low NW lanes of each 16-lane row (NW<=16,
// pattern must repeat with period NW within the row). Valid in lane NW-1.
template <int NW>
__device__ __forceinline__ unsigned long long row_max_u64(unsigned long long k) {
#define STEPU_(ctrl)                                                                    \
  {                                                                                     \
    unsigned lo_ = (unsigned)k, hi_ = (unsigned)(k >> 32);                              \
    unsigned plo_ = (unsigned)__builtin_amdgcn_update_dpp((int)lo_, (int)lo_, ctrl,     \
                                                          0xf, 0xf, false);             \
    unsigned phi_ = (unsigned)__builtin_amdgcn_update_dpp((int)hi_, (int)hi_, ctrl,     \
                                                          0xf, 0xf, false);             \
    unsigned long long pk_ = ((unsigned long long)phi_ << 32) | plo_;                   \
    k = (pk_ > k) ? pk_ : k;                                                            \
  }
  if constexpr (NW > 1) STEPU_(0x111)
  if constexpr (NW > 2) STEPU_(0x112)
  if constexpr (NW > 4) STEPU_(0x114)
  if constexpr (NW > 8) STEPU_(0x118)
#undef STEPU_
  return k;
}

__device__ __forceinline__ float readlane_f32(float x, int l) {
  return __int_as_float(__builtin_amdgcn_readlane(__float_as_int(x), l));
}

// ---------------------------------------------------------------------------
// prep: split x; write packed c4 = {x,y,z,|c|^2}, normal, plane, f0
// ---------------------------------------------------------------------------
__global__ void prep_kernel(const float* __restrict__ x,
                            const float* __restrict__ W_in,
                            const float* __restrict__ b_in,
                            float4* __restrict__ c4, float* __restrict__ nrm,
                            float* __restrict__ pl, float* __restrict__ f0) {
  int i = blockIdx.x * 256 + threadIdx.x;
  if (i >= B * N0) return;
  const float* xp = x + (size_t)i * 7;
  float cx = xp[0], cy = xp[1], cz = xp[2];
  // tie-sensitive (feeds kNN distance): exact fp32, ref association order
  float kk = __fadd_rn(__fadd_rn(__fmul_rn(cx, cx), __fmul_rn(cy, cy)), __fmul_rn(cz, cz));
  c4[i] = make_float4(cx, cy, cz, kk);
  nrm[i * 3 + 0] = xp[3]; nrm[i * 3 + 1] = xp[4]; nrm[i * 3 + 2] = xp[5];
  pl[i] = xp[6];
#pragma unroll
  for (int o = 0; o < 8; o++) {
    f0[(size_t)i * 8 + o] = cx * W_in[o * 3 + 0] + cy * W_in[o * 3 + 1] + cz * W_in[o * 3 + 2] + b_in[o];
  }
}

// ---------------------------------------------------------------------------
// kNN: wave per query. Lane owns M=Nk/64 candidates (strided, coalesced).
// 16 rounds of DPP wave argmin (tie -> smaller index, matches stable top_k).
// launch_bounds(256,2) for M=64: VGPR cap 256 so d[64] stays in registers
// (R3 spilled at VGPR_Count=64 -> 1.13 GB scratch traffic).
// ---------------------------------------------------------------------------
template <int M>
__global__ __launch_bounds__(256, (M >= 64) ? 2 : 4)
void knn_kernel(const float4* __restrict__ q4, const float4* __restrict__ k4,
                int Q, int Nk, int* __restrict__ out) {
  int gt = blockIdx.x * 256 + threadIdx.x;
  int bq = gt >> 6;
  int lane = gt & 63;
  int b = bq / Q;
  float4 q = q4[bq];
  const float4* kb = k4 + (size_t)b * Nk;
  float d[M];
#pragma unroll
  for (int i = 0; i < M; i++) {
    float4 kp = kb[i * 64 + lane];
    float dot = __fadd_rn(__fadd_rn(__fmul_rn(q.x, kp.x), __fmul_rn(q.y, kp.y)),
                          __fmul_rn(q.z, kp.z));
    d[i] = __fadd_rn(__fsub_rn(q.w, __fmul_rn(2.0f, dot)), kp.w);
  }
  unsigned long long mask = 0ull;
  float lv = 3.0e38f; int li = 0;
#pragma unroll
  for (int i = 0; i < M; i++) { if (d[i] < lv) { lv = d[i]; li = i; } }
  int mynb = 0;
  for (int r = 0; r < KNB; r++) {
    int n = li * 64 + lane;
    float wmin = wave_min_bcast_f32(lv);
    unsigned ci = (lv == wmin) ? (unsigned)n : 0xFFFFFFFFu;
    int wn = (int)wave_min_bcast_u32(ci);
    if (lane == r) mynb = wn;
    if (lane == (wn & 63)) {  // this lane owned the winner: mark + rescan
      mask |= 1ull << (wn >> 6);
      lv = 3.0e38f; li = 0;
#pragma unroll
      for (int i = 0; i < M; i++) {
        bool dead = (mask >> i) & 1ull;
        float dv = dead ? 3.0e38f : d[i];
        if (dv < lv) { lv = dv; li = i; }
      }
    }
  }
  if (lane < KNB) out[(size_t)bq * KNB + lane] = mynb;
}

// ---------------------------------------------------------------------------
// ctrY[b,q,o] = sum_c fq[b,q,c] * W[o, CF+c]   (K-independent half of conv)
// ---------------------------------------------------------------------------
template <int CF, int CO>
__global__ void ctry_kernel(const float* __restrict__ fq, const float* __restrict__ W,
                            float* __restrict__ ctrY, int total) {
  int i = blockIdx.x * 256 + threadIdx.x;
  if (i >= total) return;
  int o = i % CO, bq = i / CO;
  const float* fp = fq + (size_t)bq * CF;
  const float* wp = W + (size_t)o * (2 * CF) + CF;
  float acc = 0.f;
#pragma unroll
  for (int c = 0; c < CF; c++) acc = fmaf(fp[c], wp[c], acc);
  ctrY[i] = acc;
}

// ---------------------------------------------------------------------------
// edge-conv pass A: wave per (b,q); lane = g*16+k (g: o-chunk==GN group, k: nbr)
// y = Wl*(nb-ctr) + ctrY; min/max over k per channel; per-(b,group) sum/sumsq.
// ---------------------------------------------------------------------------
template <int CF, int CO>
__global__ __launch_bounds__(256) void edgeconv_kernel(
    const float* __restrict__ fq, const float* __restrict__ fk,
    const int* __restrict__ knn, const float* __restrict__ Wfull,
    const float* __restrict__ ctrY,
    float* __restrict__ ymin, float* __restrict__ ymax,
    float* __restrict__ gstats, int Q, int Nk) {
  constexpr int J = CO / 4;
  constexpr int SEC = J * CF + 8;
  __shared__ float Wl[4 * SEC];
  __shared__ float sstat[8];
  for (int t = threadIdx.x; t < CO * CF; t += 256) {
    int o = t / CF, c = t % CF;
    Wl[(o / J) * SEC + (o % J) * CF + c] = Wfull[(size_t)o * (2 * CF) + c];
  }
  if (threadIdx.x < 8) sstat[threadIdx.x] = 0.0f;
  __syncthreads();
  const int wid = threadIdx.x >> 6, lane = threadIdx.x & 63;
  const int bq = blockIdx.x * 4 + wid;
  const int b = bq / Q;
  const int g = lane >> 4, k = lane & 15;
  const int ni = knn[(size_t)bq * KNB + k];
  const float* nbp = fk + (size_t)(b * Nk + ni) * CF;
  const float* cp  = fq + (size_t)bq * CF;
  float acc[J];
#pragma unroll
  for (int j = 0; j < J; j++) acc[j] = 0.0f;
  const float* wg = &Wl[g * SEC];
#pragma unroll
  for (int c = 0; c < CF; c += 4) {
    float4 nb4 = *(const float4*)(nbp + c);
    float4 c4  = *(const float4*)(cp + c);
    float e0 = nb4.x - c4.x, e1 = nb4.y - c4.y, e2 = nb4.z - c4.z, e3 = nb4.w - c4.w;
#pragma unroll
    for (int j = 0; j < J; j++) {
      float4 w4 = *(const float4*)(wg + j * CF + c);
      acc[j] = fmaf(e0, w4.x, acc[j]);
      acc[j] = fmaf(e1, w4.y, acc[j]);
      acc[j] = fmaf(e2, w4.z, acc[j]);
      acc[j] = fmaf(e3, w4.w, acc[j]);
    }
  }
  float s = 0.f, s2 = 0.f;
  const float* cyp = ctrY + (size_t)bq * CO + g * J;
#pragma unroll
  for (int j = 0; j < J; j++) {
    float y = acc[j] + cyp[j];
    acc[j] = y;            // acc becomes running max
    s += y; s2 = fmaf(y, y, s2);
  }
  float mn[J];
#pragma unroll
  for (int j = 0; j < J; j++) mn[j] = acc[j];
#pragma unroll
  for (int m = 1; m < 16; m <<= 1) {  // reduce over the 16 k-lanes
#pragma unroll
    for (int j = 0; j < J; j++) {
      float a = __shfl_xor(acc[j], m); if (a > acc[j]) acc[j] = a;
      float c2 = __shfl_xor(mn[j], m); if (c2 < mn[j]) mn[j] = c2;
    }
    s  += __shfl_xor(s, m);
    s2 += __shfl_xor(s2, m);
  }
  if (k == 0) {
    float* mnp = ymin + (size_t)bq * CO + g * J;
    float* mxp = ymax + (size_t)bq * CO + g * J;
#pragma unroll
    for (int j = 0; j < J; j++) { mnp[j] = mn[j]; mxp[j] = acc[j]; }
    atomicAdd(&sstat[g], s);
    atomicAdd(&sstat[4 + g], s2);
  }
  __syncthreads();
  if (threadIdx.x < 8) atomicAdd(&gstats[b * 8 + threadIdx.x], sstat[threadIdx.x]);
}

// ---------------------------------------------------------------------------
// pass B (gn_final fused): m/rs computed per-thread from gstats;
// f = lrelu((sel - m)*gw*rs + gb), sel = max if scale>=0 else min.
// ---------------------------------------------------------------------------
template <int CO>
__global__ void gn_out_kernel(const float* __restrict__ ymin, const float* __restrict__ ymax,
                              const float* __restrict__ gstats, const float* __restrict__ gw,
                              const float* __restrict__ gb, float* __restrict__ fout,
                              int total, int Q, float inv_cnt) {
  int i = blockIdx.x * 256 + threadIdx.x;
  if (i >= total) return;
  constexpr int J = CO / 4;
  int o = i % CO; int bq = i / CO; int b = bq / Q;
  int g = o / J;
  float m  = gstats[b * 8 + g] * inv_cnt;
  float s2 = gstats[b * 8 + 4 + g] * inv_cnt;
  float rs = rsqrtf(s2 - m * m + 1e-5f);
  float sc = gw[o] * rs;
  float sel = (sc >= 0.f) ? ymax[i] : ymin[i];
  float v = (sel - m) * sc + gb[o];
  fout[i] = (v > 0.f) ? v : 0.2f * v;
}

// ---------------------------------------------------------------------------
// FPS v4: block per batch, BLK=512 (2 waves/SIMD). CONTIGUOUS ownership
// (bi = tid*M+i) so min-index tie-break == min-lane -> intra-wave argmax is
// one f32 DPP max chain + ballot/ffs (no second DPP chain). Wave leader posts
// {key,coords} to ping-pong per-wave slots; after ONE barrier, lanes 0..NW-1
// load slots, 3-step row-DPP u64 reduce, readlane -> winner key+coords.
// Key = (dist_bits<<12)|(4095-bi): u64 max == (max dist, tie min index),
// exact jnp.argmax semantics (dists >= 0 so float bits are monotone).
// ---------------------------------------------------------------------------
template <int NPTS, int BLK>
__global__ __launch_bounds__(BLK) void fps_kernel(const float4* __restrict__ c4,
                                                  int* __restrict__ idx_out, int num) {
  constexpr int M = NPTS / BLK;
  constexpr int NW = BLK / 64;
  __shared__ unsigned long long skey[2][NW];
  __shared__ float4 scrd[2][NW];
  const int b = blockIdx.x, tid = threadIdx.x;
  const int wid = tid >> 6, lane = tid & 63;
  const float4* cb = c4 + (size_t)b * NPTS;
  float cx[M], cy[M], cz[M], dist[M];
#pragma unroll
  for (int i = 0; i < M; i++) {
    float4 p = cb[tid * M + i];
    cx[i] = p.x; cy[i] = p.y; cz[i] = p.z;
    dist[i] = 3.4e38f;
  }
  if (tid == 0) idx_out[(size_t)b * num] = 0;
  float4 p0 = cb[0];
  float px = p0.x, py = p0.y, pz = p0.z;
  for (int t = 1; t < num; t++) {
    float bv = -1.f; int bi = 0;
    float bx = 0.f, by = 0.f, bz = 0.f;
#pragma unroll
    for (int i = 0; i < M; i++) {
      float dx = __fsub_rn(cx[i], px), dy = __fsub_rn(cy[i], py), dz = __fsub_rn(cz[i], pz);
      float d = __fadd_rn(__fadd_rn(__fmul_rn(dx, dx), __fmul_rn(dy, dy)), __fmul_rn(dz, dz));
      float dd = dist[i]; dd = (d < dd) ? d : dd; dist[i] = dd;
      if (dd > bv) { bv = dd; bi = tid * M + i; bx = cx[i]; by = cy[i]; bz = cz[i]; }
    }
    float wv = wave_max_bcast_f32(bv);
    unsigned long long bal = __ballot(bv == wv);
    int wl = __ffsll(bal) - 1;   // lowest tied lane == smallest bi (contiguous)
    int p = t & 1;
    if (lane == wl) {
      skey[p][wid] = ((unsigned long long)__float_as_uint(wv) << 12) | (unsigned)(4095 - bi);
      scrd[p][wid] = make_float4(bx, by, bz, 0.f);
    }
    __syncthreads();
    unsigned long long k = skey[p][lane & (NW - 1)];
    float4 cc = scrd[p][lane & (NW - 1)];
    unsigned long long r = row_max_u64<NW>(k);
    unsigned long long wkey =
        ((unsigned long long)(unsigned)__builtin_amdgcn_readlane((int)(r >> 32), NW - 1) << 32) |
        (unsigned)__builtin_amdgcn_readlane((int)(unsigned)r, NW - 1);
    unsigned long long bal2 = __ballot(k == wkey);
    int sl = __ffsll(bal2) - 1;
    px = readlane_f32(cc.x, sl);
    py = readlane_f32(cc.y, sl);
    pz = readlane_f32(cc.z, sl);
    if (tid == 0) idx_out[(size_t)b * num + t] = 4095 - (int)(wkey & 0xFFFull);
  }
}

// ---------------------------------------------------------------------------
// gather at FPS indices: packed c4, (optional) 3-packed coords, normal, plane, f
// ---------------------------------------------------------------------------
template <int CF>
__global__ void gather_kernel(const int* __restrict__ idx,
                              const float4* __restrict__ c4s, const float* __restrict__ nrms,
                              const float* __restrict__ pls, const float* __restrict__ fs,
                              float4* __restrict__ c4d, float* __restrict__ cd3,
                              float* __restrict__ nd, float* __restrict__ pd,
                              float* __restrict__ fd, int Nsrc, int num) {
  int i = blockIdx.x * 256 + threadIdx.x;
  if (i >= B * num) return;
  int b = i / num;
  int src = b * Nsrc + idx[i];
  float4 c = c4s[src];
  c4d[i] = c;
  cd3[i * 3 + 0] = c.x; cd3[i * 3 + 1] = c.y; cd3[i * 3 + 2] = c.z;
  nd[i * 3 + 0] = nrms[(size_t)src * 3 + 0];
  nd[i * 3 + 1] = nrms[(size_t)src * 3 + 1];
  nd[i * 3 + 2] = nrms[(size_t)src * 3 + 2];
  pd[i] = pls[src];
#pragma unroll 4
  for (int c2 = 0; c2 < CF; c2++) fd[(size_t)i * CF + c2] = fs[(size_t)src * CF + c2];
}

// ---------------------------------------------------------------------------
extern "C" void kernel_launch(void* const* d_in, const int* in_sizes, int n_in,
                              void* d_out, int out_size, void* d_ws, size_t ws_size,
                              hipStream_t stream) {
  (void)in_sizes; (void)n_in; (void)out_size; (void)ws_size;
  const float* x    = (const float*)d_in[0];
  const float* W_in = (const float*)d_in[1];
  const float* b_in = (const float*)d_in[2];
  const float* W1   = (const float*)d_in[3];
  const float* g1w  = (const float*)d_in[4];
  const float* g1b  = (const float*)d_in[5];
  const float* W2   = (const float*)d_in[6];
  const float* g2w  = (const float*)d_in[7];
  const float* g2b  = (const float*)d_in[8];
  const float* W3   = (const float*)d_in[9];
  const float* g3w  = (const float*)d_in[10];
  const float* g3b  = (const float*)d_in[11];
  const float* W4   = (const float*)d_in[12];
  const float* g4w  = (const float*)d_in[13];
  const float* g4b  = (const float*)d_in[14];

  float* ws = (float*)d_ws;
  size_t o_c40  = 0;                                         // float4-aligned (ws base)
  size_t o_nrm  = o_c40  + (size_t)B * N0 * 4;
  size_t o_pl   = o_nrm  + (size_t)B * N0 * 3;
  size_t o_f0   = o_pl   + (size_t)B * N0;
  size_t o_f1   = o_f0   + (size_t)B * N0 * 8;
  size_t o_ctrY = o_f1   + (size_t)B * N0 * 32;
  size_t o_ymin = o_ctrY + (size_t)B * N0 * 32;
  size_t o_ymax = o_ymin + (size_t)B * N0 * 32;
  size_t o_knn  = o_ymax + (size_t)B * N0 * 32;              // int region
  size_t o_gst  = o_knn  + (size_t)B * N0 * KNB;
  size_t o_idx1 = o_gst  + 4 * B * 8;                        // int region
  size_t o_idx2 = o_idx1 + (size_t)B * NQ;                   // int region
  size_t o_c4q1 = o_idx2 + (size_t)B * NQ;                   // float4-aligned
  size_t o_nq1  = o_c4q1 + (size_t)B * NQ * 4;
  size_t o_pq1  = o_nq1  + (size_t)B * NQ * 3;
  size_t o_fq1  = o_pq1  + (size_t)B * NQ;
  size_t o_f2   = o_fq1  + (size_t)B * NQ * 32;
  size_t o_f3   = o_f2   + (size_t)B * NQ * 64;
  size_t o_c4q2 = o_f3   + (size_t)B * NQ * 64;              // float4-aligned
  size_t o_fq2  = o_c4q2 + (size_t)B * NQ * 4;
  size_t o_dmp3 = o_fq2  + (size_t)B * NQ * 64;              // dummy 3-packed coords

  float4* c40  = (float4*)(ws + o_c40);
  float*  nrm  = ws + o_nrm;   float* pl   = ws + o_pl;
  float*  f0   = ws + o_f0;    float* f1   = ws + o_f1;
  float*  ctrY = ws + o_ctrY;  float* ymin = ws + o_ymin;  float* ymax = ws + o_ymax;
  int*    knn  = (int*)(ws + o_knn);
  float*  gst  = ws + o_gst;
  int*    idx1 = (int*)(ws + o_idx1);
  int*    idx2 = (int*)(ws + o_idx2);
  float4* c4q1 = (float4*)(ws + o_c4q1);
  float*  nq1  = ws + o_nq1;   float* pq1  = ws + o_pq1;   float* fq1 = ws + o_fq1;
  float*  f2   = ws + o_f2;    float* f3   = ws + o_f3;
  float4* c4q2 = (float4*)(ws + o_c4q2);
  float*  fq2  = ws + o_fq2;
  float*  dmp3 = ws + o_dmp3;

  float* out  = (float*)d_out;
  float* cq2  = out;                                   // (B,NQ,3)
  float* fout = out + (size_t)B * NQ * 3;              // (B,NQ,128)
  float* nq2  = fout + (size_t)B * NQ * 128;           // (B,NQ,3)
  float* pq2  = nq2 + (size_t)B * NQ * 3;              // (B,NQ,1)

  hipMemsetAsync(gst, 0, 4 * B * 8 * sizeof(float), stream);

  // stage 0
  prep_kernel<<<(B * N0 + 255) / 256, 256, 0, stream>>>(x, W_in, b_in, c40, nrm, pl, f0);

  // ---- layer 1: Q=4096, keys=4096, CF=8, CO=32 ----
  ctry_kernel<8, 32><<<(B * N0 * 32 + 255) / 256, 256, 0, stream>>>(f0, W1, ctrY, B * N0 * 32);
  knn_kernel<64><<<B * N0 * 64 / 256, 256, 0, stream>>>(c40, c40, N0, N0, knn);
  edgeconv_kernel<8, 32><<<B * N0 / 4, 256, 0, stream>>>(f0, f0, knn, W1, ctrY, ymin, ymax, gst + 0, N0, N0);
  gn_out_kernel<32><<<(B * N0 * 32 + 255) / 256, 256, 0, stream>>>(ymin, ymax, gst + 0, g1w, g1b, f1, B * N0 * 32, N0, 1.0f / (4096.0f * 16.0f * 8.0f));

  // FPS 1 + gather
  fps_kernel<4096, 512><<<B, 512, 0, stream>>>(c40, idx1, NQ);
  gather_kernel<32><<<(B * NQ + 255) / 256, 256, 0, stream>>>(idx1, c40, nrm, pl, f1,
                                                              c4q1, dmp3, nq1, pq1, fq1, N0, NQ);

  // ---- layer 2: Q=1024, keys=4096, CF=32, CO=64 ----
  ctry_kernel<32, 64><<<(B * NQ * 64 + 255) / 256, 256, 0, stream>>>(fq1, W2, ctrY, B * NQ * 64);
  knn_kernel<64><<<B * NQ * 64 / 256, 256, 0, stream>>>(c4q1, c40, NQ, N0, knn);
  edgeconv_kernel<32, 64><<<B * NQ / 4, 256, 0, stream>>>(fq1, f1, knn, W2, ctrY, ymin, ymax, gst + B * 8, NQ, N0);
  gn_out_kernel<64><<<(B * NQ * 64 + 255) / 256, 256, 0, stream>>>(ymin, ymax, gst + B * 8, g2w, g2b, f2, B * NQ * 64, NQ, 1.0f / (1024.0f * 16.0f * 16.0f));

  // ---- layer 3: Q=1024, keys=1024, CF=64, CO=64 ----
  ctry_kernel<64, 64><<<(B * NQ * 64 + 255) / 256, 256, 0, stream>>>(f2, W3, ctrY, B * NQ * 64);
  knn_kernel<16><<<B * NQ * 64 / 256, 256, 0, stream>>>(c4q1, c4q1, NQ, NQ, knn);
  edgeconv_kernel<64, 64><<<B * NQ / 4, 256, 0, stream>>>(f2, f2, knn, W3, ctrY, ymin, ymax, gst + 2 * B * 8, NQ, NQ);
  gn_out_kernel<64><<<(B * NQ * 64 + 255) / 256, 256, 0, stream>>>(ymin, ymax, gst + 2 * B * 8, g3w, g3b, f3, B * NQ * 64, NQ, 1.0f / (1024.0f * 16.0f * 16.0f));

  // FPS 2 + gather (coor_q/normal_q/plane_q go straight to d_out)
  fps_kernel<1024, 512><<<B, 512, 0, stream>>>(c4q1, idx2, NQ);
  gather_kernel<64><<<(B * NQ + 255) / 256, 256, 0, stream>>>(idx2, c4q1, nq1, pq1, f3,
                                                              c4q2, cq2, nq2, pq2, fq2, NQ, NQ);

  // ---- layer 4: Q=1024, keys=1024, CF=64, CO=128 ----
  ctry_kernel<64, 128><<<(B * NQ * 128 + 255) / 256, 256, 0, stream>>>(fq2, W4, ctrY, B * NQ * 128);
  knn_kernel<16><<<B * NQ * 64 / 256, 256, 0, stream>>>(c4q2, c4q1, NQ, NQ, knn);
  edgeconv_kernel<64, 128><<<B * NQ / 4, 256, 0, stream>>>(fq2, f3, knn, W4, ctrY, ymin, ymax, gst + 3 * B * 8, NQ, NQ);
  gn_out_kernel<128><<<(B * NQ * 128 + 255) / 256, 256, 0, stream>>>(ymin, ymax, gst + 3 * B * 8, g4w, g4b, fout, B * NQ * 128, NQ, 1.0f / (1024.0f * 16.0f * 32.0f));
}

// Round 5
// 1869.731 us; speedup vs baseline: 1.5003x; 1.3406x over previous
//
#include <hip/hip_runtime.h>
#include <cstdint>

static constexpr int B   = 8;
static constexpr int N0  = 4096;
static constexpr int NQ  = 1024;
static constexpr int KNB = 16;

// ---------------------------------------------------------------------------
// DPP wave reductions (no DS ops). row_shr 1,2,4,8 + row_bcast15/31;
// full-wave result in lane 63. update_dpp(old=x, src=x): invalid lanes keep x.
// ---------------------------------------------------------------------------
__device__ __forceinline__ float wave_max_bcast_f32(float x) {
#define STEP_(ctrl)                                                                     \
  {                                                                                     \
    int t_ = __builtin_amdgcn_update_dpp(__float_as_int(x), __float_as_int(x), ctrl,    \
                                         0xf, 0xf, false);                              \
    x = fmaxf(x, __int_as_float(t_));                                                   \
  }
  STEP_(0x111) STEP_(0x112) STEP_(0x114) STEP_(0x118) STEP_(0x142) STEP_(0x143)
#undef STEP_
  return __int_as_float(__builtin_amdgcn_readlane(__float_as_int(x), 63));
}

__device__ __forceinline__ float wave_min_bcast_f32(float x) {
#define STEP_(ctrl)                                                                     \
  {                                                                                     \
    int t_ = __builtin_amdgcn_update_dpp(__float_as_int(x), __float_as_int(x), ctrl,    \
                                         0xf, 0xf, false);                              \
    x = fminf(x, __int_as_float(t_));                                                   \
  }
  STEP_(0x111) STEP_(0x112) STEP_(0x114) STEP_(0x118) STEP_(0x142) STEP_(0x143)
#undef STEP_
  return __int_as_float(__builtin_amdgcn_readlane(__float_as_int(x), 63));
}

__device__ __forceinline__ unsigned wave_min_bcast_u32(unsigned x) {
#define STEP_(ctrl)                                                                     \
  {                                                                                     \
    unsigned t_ = (unsigned)__builtin_amdgcn_update_dpp((int)x, (int)x, ctrl,           \
                                                        0xf, 0xf, false);               \
    x = (t_ < x) ? t_ : x;                                                              \
  }
  STEP_(0x111) STEP_(0x112) STEP_(0x114) STEP_(0x118) STEP_(0x142) STEP_(0x143)
#undef STEP_
  return (unsigned)__builtin_amdgcn_readlane((int)x, 63);
}

// Row-confined u64 max over the low NW lanes of each 16-lane row (NW<=16).
// Valid in lane NW-1 (pattern repeats with period NW within the row).
template <int NW>
__device__ __forceinline__ unsigned long long row_max_u64(unsigned long long k) {
#define STEPU_(ctrl)                                                                    \
  {                                                                                     \
    unsigned lo_ = (unsigned)k, hi_ = (unsigned)(k >> 32);                              \
    unsigned plo_ = (unsigned)__builtin_amdgcn_update_dpp((int)lo_, (int)lo_, ctrl,     \
                                                          0xf, 0xf, false);             \
    unsigned phi_ = (unsigned)__builtin_amdgcn_update_dpp((int)hi_, (int)hi_, ctrl,     \
                                                          0xf, 0xf, false);             \
    unsigned long long pk_ = ((unsigned long long)phi_ << 32) | plo_;                   \
    k = (pk_ > k) ? pk_ : k;                                                            \
  }
  if constexpr (NW > 1) STEPU_(0x111)
  if constexpr (NW > 2) STEPU_(0x112)
  if constexpr (NW > 4) STEPU_(0x114)
  if constexpr (NW > 8) STEPU_(0x118)
#undef STEPU_
  return k;
}

__device__ __forceinline__ float readlane_f32(float x, int l) {
  return __int_as_float(__builtin_amdgcn_readlane(__float_as_int(x), l));
}

// ---------------------------------------------------------------------------
// prep: split x; write packed c4 = {x,y,z,|c|^2}, normal, plane, f0
// ---------------------------------------------------------------------------
__global__ void prep_kernel(const float* __restrict__ x,
                            const float* __restrict__ W_in,
                            const float* __restrict__ b_in,
                            float4* __restrict__ c4, float* __restrict__ nrm,
                            float* __restrict__ pl, float* __restrict__ f0) {
  int i = blockIdx.x * 256 + threadIdx.x;
  if (i >= B * N0) return;
  const float* xp = x + (size_t)i * 7;
  float cx = xp[0], cy = xp[1], cz = xp[2];
  // tie-sensitive (feeds kNN distance): exact fp32, ref association order
  float kk = __fadd_rn(__fadd_rn(__fmul_rn(cx, cx), __fmul_rn(cy, cy)), __fmul_rn(cz, cz));
  c4[i] = make_float4(cx, cy, cz, kk);
  nrm[i * 3 + 0] = xp[3]; nrm[i * 3 + 1] = xp[4]; nrm[i * 3 + 2] = xp[5];
  pl[i] = xp[6];
#pragma unroll
  for (int o = 0; o < 8; o++) {
    f0[(size_t)i * 8 + o] = cx * W_in[o * 3 + 0] + cy * W_in[o * 3 + 1] + cz * W_in[o * 3 + 2] + b_in[o];
  }
}

// ---------------------------------------------------------------------------
// kNN body: wave per query (bq). Lane owns M=Nk/64 candidates.
// 16 rounds of DPP wave argmin (tie -> smaller index == stable top_k).
// d2 = ((|q|^2 - 2*dot) + |k|^2), exact fp32 non-fused like the reference.
// ---------------------------------------------------------------------------
template <int M>
__device__ __forceinline__ void knn_body(int bq, int lane,
                                         const float4* __restrict__ q4,
                                         const float4* __restrict__ k4,
                                         int Q, int Nk, int* __restrict__ out) {
  int b = bq / Q;
  float4 q = q4[bq];
  const float4* kb = k4 + (size_t)b * Nk;
  float d[M];
#pragma unroll
  for (int i = 0; i < M; i++) {
    float4 kp = kb[i * 64 + lane];
    float dot = __fadd_rn(__fadd_rn(__fmul_rn(q.x, kp.x), __fmul_rn(q.y, kp.y)),
                          __fmul_rn(q.z, kp.z));
    d[i] = __fadd_rn(__fsub_rn(q.w, __fmul_rn(2.0f, dot)), kp.w);
  }
  unsigned long long mask = 0ull;
  float lv = 3.0e38f; int li = 0;
#pragma unroll
  for (int i = 0; i < M; i++) { if (d[i] < lv) { lv = d[i]; li = i; } }
  int mynb = 0;
  for (int r = 0; r < KNB; r++) {
    int n = li * 64 + lane;
    float wmin = wave_min_bcast_f32(lv);
    unsigned ci = (lv == wmin) ? (unsigned)n : 0xFFFFFFFFu;
    int wn = (int)wave_min_bcast_u32(ci);
    if (lane == r) mynb = wn;
    if (lane == (wn & 63)) {  // owner lane: mark + rescan
      mask |= 1ull << (wn >> 6);
      lv = 3.0e38f; li = 0;
#pragma unroll
      for (int i = 0; i < M; i++) {
        bool dead = (mask >> i) & 1ull;
        float dv = dead ? 3.0e38f : d[i];
        if (dv < lv) { lv = dv; li = i; }
      }
    }
  }
  if (lane < KNB) out[(size_t)bq * KNB + lane] = mynb;
}

// ---------------------------------------------------------------------------
// ctrY body: ctrY[b,q,o] = sum_c fq_row[c] * W[o, CF+c]; optional row
// indirection (fq_row = fq[b*Nsrc + ridx[bq]]) replaces the f-gather.
// ---------------------------------------------------------------------------
template <int CF, int CO>
__device__ __forceinline__ void ctry_body(int i, int total, const float* __restrict__ fq,
                                          const float* __restrict__ W,
                                          float* __restrict__ ctrY,
                                          const int* __restrict__ ridx, int Q, int Nsrc) {
  if (i >= total) return;
  int o = i % CO, bq = i / CO;
  const float* fp;
  if (ridx) {
    int b = bq / Q;
    fp = fq + ((size_t)b * Nsrc + ridx[bq]) * CF;
  } else {
    fp = fq + (size_t)bq * CF;
  }
  const float* wp = W + (size_t)o * (2 * CF) + CF;
  float acc = 0.f;
#pragma unroll
  for (int c = 0; c < CF; c++) acc = fmaf(fp[c], wp[c], acc);
  ctrY[i] = acc;
}

// ---------------------------------------------------------------------------
// FPS body: BLK=512, one block per batch, selects NQ=1024 points.
// Coords in registers; contiguous ownership (bi = tid*M+i) so min-index
// tie-break == min-lane; DPP argmax + ballot; ONE barrier/iter (ping-pong
// wave slots); NO global ops inside the loop (winners buffered in w0/w1:
// thread tid keeps winners t==tid and t==tid+512) -> no vmcnt(0) drain at
// the barrier. Key = (dist_bits<<12)|(4095-bi): u64 max == (max dist, tie
// min index) exactly (dists >= 0), matching jnp.argmax.
// ---------------------------------------------------------------------------
template <int NPTS>
__device__ __forceinline__ void fps_body(const float4* __restrict__ cb,
                                         int& w0, int& w1) {
  constexpr int BLK = 512;
  constexpr int M = NPTS / BLK;
  constexpr int NW = BLK / 64;
  __shared__ unsigned long long skey[2][NW];
  __shared__ float4 scrd[2][NW];
  const int tid = threadIdx.x;
  const int wid = tid >> 6, lane = tid & 63;
  float cx[M], cy[M], cz[M], dist[M];
#pragma unroll
  for (int i = 0; i < M; i++) {
    float4 p = cb[tid * M + i];
    cx[i] = p.x; cy[i] = p.y; cz[i] = p.z;
    dist[i] = 3.4e38f;
  }
  float4 p0 = cb[0];
  float px = p0.x, py = p0.y, pz = p0.z;
  w0 = 0; w1 = 0;
  for (int t = 1; t < NQ; t++) {
    float bv = -1.f; int bi = 0;
    float bx = 0.f, by = 0.f, bz = 0.f;
#pragma unroll
    for (int i = 0; i < M; i++) {
      float dx = __fsub_rn(cx[i], px), dy = __fsub_rn(cy[i], py), dz = __fsub_rn(cz[i], pz);
      float d = __fadd_rn(__fadd_rn(__fmul_rn(dx, dx), __fmul_rn(dy, dy)), __fmul_rn(dz, dz));
      float dd = dist[i]; dd = (d < dd) ? d : dd; dist[i] = dd;
      if (dd > bv) { bv = dd; bi = tid * M + i; bx = cx[i]; by = cy[i]; bz = cz[i]; }
    }
    float wv = wave_max_bcast_f32(bv);
    unsigned long long bal = __ballot(bv == wv);
    int wl = __ffsll(bal) - 1;   // lowest tied lane == smallest bi (contiguous)
    int p = t & 1;
    if (lane == wl) {
      skey[p][wid] = ((unsigned long long)__float_as_uint(wv) << 12) | (unsigned)(4095 - bi);
      scrd[p][wid] = make_float4(bx, by, bz, 0.f);
    }
    __syncthreads();
    unsigned long long k = skey[p][lane & (NW - 1)];
    float4 cc = scrd[p][lane & (NW - 1)];
    unsigned long long r = row_max_u64<NW>(k);
    unsigned long long wkey =
        ((unsigned long long)(unsigned)__builtin_amdgcn_readlane((int)(r >> 32), NW - 1) << 32) |
        (unsigned)__builtin_amdgcn_readlane((int)(unsigned)r, NW - 1);
    unsigned long long bal2 = __ballot(k == wkey);
    int sl = __ffsll(bal2) - 1;
    px = readlane_f32(cc.x, sl);
    py = readlane_f32(cc.y, sl);
    pz = readlane_f32(cc.z, sl);
    int win = 4095 - (int)(wkey & 0xFFFull);
    if (t == tid) w0 = win;
    if (t == tid + 512) w1 = win;
  }
}

// ---------------------------------------------------------------------------
// mega1: blocks [0,8) fps1 (+ coord/nrm/pl gather tail); [8,8+4096) knn1;
// rest ctry1. All roles depend only on prep outputs; no inter-block deps.
// ---------------------------------------------------------------------------
__global__ __launch_bounds__(512, 2) void mega1_kernel(
    const float4* __restrict__ c40, const float* __restrict__ nrm,
    const float* __restrict__ pl, const float* __restrict__ f0,
    const float* __restrict__ W1, int* __restrict__ idx1,
    float4* __restrict__ c4q1, float* __restrict__ nq1, float* __restrict__ pq1,
    int* __restrict__ knn1, float* __restrict__ ctrY1) {
  int blk = blockIdx.x;
  if (blk < 8) {
    const int b = blk, tid = threadIdx.x;
    const float4* cb = c40 + (size_t)b * N0;
    int w0, w1;
    fps_body<N0>(cb, w0, w1);
    int rows[2] = {tid, tid + 512};
    int srcs[2] = {(tid == 0) ? 0 : w0, w1};
    int* idxb = idx1 + (size_t)b * NQ;
#pragma unroll
    for (int u = 0; u < 2; u++) {
      int r = rows[u], s = srcs[u];
      idxb[r] = s;
      c4q1[(size_t)b * NQ + r] = cb[s];
      const float* np = nrm + ((size_t)b * N0 + s) * 3;
      float* ndp = nq1 + ((size_t)b * NQ + r) * 3;
      ndp[0] = np[0]; ndp[1] = np[1]; ndp[2] = np[2];
      pq1[(size_t)b * NQ + r] = pl[(size_t)b * N0 + s];
    }
  } else if (blk < 8 + 4096) {
    int bq = (blk - 8) * 8 + (threadIdx.x >> 6);
    knn_body<64>(bq, threadIdx.x & 63, c40, c40, N0, N0, knn1);
  } else {
    int i = (blk - (8 + 4096)) * 512 + threadIdx.x;
    ctry_body<8, 32>(i, B * N0 * 32, f0, W1, ctrY1, nullptr, 0, 0);
  }
}

// ---------------------------------------------------------------------------
// mega2: blocks [0,8) fps2 (+ gather tail -> c4q2, d_out coords/normal/plane);
// [8,1032) knn2 (c4q1 vs c40); [1032,2056) knn3 (c4q1 vs c4q1); rest ctry2.
// All roles depend only on {mega1, gn_out1} outputs.
// ---------------------------------------------------------------------------
__global__ __launch_bounds__(512, 2) void mega2_kernel(
    const float4* __restrict__ c40, const float4* __restrict__ c4q1,
    const float* __restrict__ nq1, const float* __restrict__ pq1,
    const float* __restrict__ f1, const int* __restrict__ idx1,
    const float* __restrict__ W2, int* __restrict__ idx2,
    float4* __restrict__ c4q2, float* __restrict__ cq2out,
    float* __restrict__ nq2out, float* __restrict__ pq2out,
    int* __restrict__ knn2, int* __restrict__ knn3, float* __restrict__ ctrY2) {
  int blk = blockIdx.x;
  if (blk < 8) {
    const int b = blk, tid = threadIdx.x;
    const float4* cqb = c4q1 + (size_t)b * NQ;
    int w0, w1;
    fps_body<NQ>(cqb, w0, w1);
    int rows[2] = {tid, tid + 512};
    int srcs[2] = {(tid == 0) ? 0 : w0, w1};
    int* idxb = idx2 + (size_t)b * NQ;
#pragma unroll
    for (int u = 0; u < 2; u++) {
      int r = rows[u], s = srcs[u];
      idxb[r] = s;
      float4 c = cqb[s];
      c4q2[(size_t)b * NQ + r] = c;
      float* cd = cq2out + ((size_t)b * NQ + r) * 3;
      cd[0] = c.x; cd[1] = c.y; cd[2] = c.z;
      const float* np = nq1 + ((size_t)b * NQ + s) * 3;
      float* ndp = nq2out + ((size_t)b * NQ + r) * 3;
      ndp[0] = np[0]; ndp[1] = np[1]; ndp[2] = np[2];
      pq2out[(size_t)b * NQ + r] = pq1[(size_t)b * NQ + s];
    }
  } else if (blk < 8 + 1024) {
    int bq = (blk - 8) * 8 + (threadIdx.x >> 6);
    knn_body<64>(bq, threadIdx.x & 63, c4q1, c40, NQ, N0, knn2);
  } else if (blk < 8 + 2048) {
    int bq = (blk - (8 + 1024)) * 8 + (threadIdx.x >> 6);
    knn_body<16>(bq, threadIdx.x & 63, c4q1, c4q1, NQ, NQ, knn3);
  } else {
    int i = (blk - (8 + 2048)) * 512 + threadIdx.x;
    ctry_body<32, 64>(i, B * NQ * 64, f1, W2, ctrY2, idx1, NQ, N0);
  }
}

// ---------------------------------------------------------------------------
// mega3: blocks [0,1024) knn4 (c4q2 vs c4q1); rest ctry4 (f3 rows via idx2).
// ---------------------------------------------------------------------------
__global__ __launch_bounds__(512, 2) void mega3_kernel(
    const float4* __restrict__ c4q1, const float4* __restrict__ c4q2,
    const float* __restrict__ f3, const int* __restrict__ idx2,
    const float* __restrict__ W4, int* __restrict__ knn4, float* __restrict__ ctrY4) {
  int blk = blockIdx.x;
  if (blk < 1024) {
    int bq = blk * 8 + (threadIdx.x >> 6);
    knn_body<16>(bq, threadIdx.x & 63, c4q2, c4q1, NQ, NQ, knn4);
  } else {
    int i = (blk - 1024) * 512 + threadIdx.x;
    ctry_body<64, 128>(i, B * NQ * 128, f3, W4, ctrY4, idx2, NQ, NQ);
  }
}

// ---------------------------------------------------------------------------
// standalone ctry (layer 3, dense)
// ---------------------------------------------------------------------------
template <int CF, int CO>
__global__ void ctry_kernel(const float* __restrict__ fq, const float* __restrict__ W,
                            float* __restrict__ ctrY, int total) {
  int i = blockIdx.x * 256 + threadIdx.x;
  ctry_body<CF, CO>(i, total, fq, W, ctrY, nullptr, 0, 0);
}

// ---------------------------------------------------------------------------
// edge-conv pass A: wave per (b,q); lane = g*16+k. y = Wl*(nb-ctr) + ctrY;
// min/max over k per channel; per-(b,group) sum/sumsq. Optional ridx:
// center row = fq[b*Nk + ridx[bq]] (replaces f-gather).
// ---------------------------------------------------------------------------
template <int CF, int CO>
__global__ __launch_bounds__(256) void edgeconv_kernel(
    const float* __restrict__ fq, const float* __restrict__ fk,
    const int* __restrict__ knn, const float* __restrict__ Wfull,
    const float* __restrict__ ctrY, const int* __restrict__ ridx,
    float* __restrict__ ymin, float* __restrict__ ymax,
    float* __restrict__ gstats, int Q, int Nk) {
  constexpr int J = CO / 4;
  constexpr int SEC = J * CF + 8;
  __shared__ float Wl[4 * SEC];
  __shared__ float sstat[8];
  for (int t = threadIdx.x; t < CO * CF; t += 256) {
    int o = t / CF, c = t % CF;
    Wl[(o / J) * SEC + (o % J) * CF + c] = Wfull[(size_t)o * (2 * CF) + c];
  }
  if (threadIdx.x < 8) sstat[threadIdx.x] = 0.0f;
  __syncthreads();
  const int wid = threadIdx.x >> 6, lane = threadIdx.x & 63;
  const int bq = blockIdx.x * 4 + wid;
  const int b = bq / Q;
  const int g = lane >> 4, k = lane & 15;
  const int ni = knn[(size_t)bq * KNB + k];
  const float* nbp = fk + (size_t)(b * Nk + ni) * CF;
  const float* cp = ridx ? fq + ((size_t)b * Nk + ridx[bq]) * CF
                         : fq + (size_t)bq * CF;
  float acc[J];
#pragma unroll
  for (int j = 0; j < J; j++) acc[j] = 0.0f;
  const float* wg = &Wl[g * SEC];
#pragma unroll
  for (int c = 0; c < CF; c += 4) {
    float4 nb4 = *(const float4*)(nbp + c);
    float4 c4  = *(const float4*)(cp + c);
    float e0 = nb4.x - c4.x, e1 = nb4.y - c4.y, e2 = nb4.z - c4.z, e3 = nb4.w - c4.w;
#pragma unroll
    for (int j = 0; j < J; j++) {
      float4 w4 = *(const float4*)(wg + j * CF + c);
      acc[j] = fmaf(e0, w4.x, acc[j]);
      acc[j] = fmaf(e1, w4.y, acc[j]);
      acc[j] = fmaf(e2, w4.z, acc[j]);
      acc[j] = fmaf(e3, w4.w, acc[j]);
    }
  }
  float s = 0.f, s2 = 0.f;
  const float* cyp = ctrY + (size_t)bq * CO + g * J;
#pragma unroll
  for (int j = 0; j < J; j++) {
    float y = acc[j] + cyp[j];
    acc[j] = y;            // acc becomes running max
    s += y; s2 = fmaf(y, y, s2);
  }
  float mn[J];
#pragma unroll
  for (int j = 0; j < J; j++) mn[j] = acc[j];
#pragma unroll
  for (int m = 1; m < 16; m <<= 1) {  // reduce over the 16 k-lanes
#pragma unroll
    for (int j = 0; j < J; j++) {
      float a = __shfl_xor(acc[j], m); if (a > acc[j]) acc[j] = a;
      float c2 = __shfl_xor(mn[j], m); if (c2 < mn[j]) mn[j] = c2;
    }
    s  += __shfl_xor(s, m);
    s2 += __shfl_xor(s2, m);
  }
  if (k == 0) {
    float* mnp = ymin + (size_t)bq * CO + g * J;
    float* mxp = ymax + (size_t)bq * CO + g * J;
#pragma unroll
    for (int j = 0; j < J; j++) { mnp[j] = mn[j]; mxp[j] = acc[j]; }
    atomicAdd(&sstat[g], s);
    atomicAdd(&sstat[4 + g], s2);
  }
  __syncthreads();
  if (threadIdx.x < 8) atomicAdd(&gstats[b * 8 + threadIdx.x], sstat[threadIdx.x]);
}

// ---------------------------------------------------------------------------
// pass B (gn_final fused): f = lrelu((sel - m)*gw*rs + gb),
// sel = max over K if scale>=0 else min (monotone-commute, exact).
// ---------------------------------------------------------------------------
template <int CO>
__global__ void gn_out_kernel(const float* __restrict__ ymin, const float* __restrict__ ymax,
                              const float* __restrict__ gstats, const float* __restrict__ gw,
                              const float* __restrict__ gb, float* __restrict__ fout,
                              int total, int Q, float inv_cnt) {
  int i = blockIdx.x * 256 + threadIdx.x;
  if (i >= total) return;
  constexpr int J = CO / 4;
  int o = i % CO; int bq = i / CO; int b = bq / Q;
  int g = o / J;
  float m  = gstats[b * 8 + g] * inv_cnt;
  float s2 = gstats[b * 8 + 4 + g] * inv_cnt;
  float rs = rsqrtf(s2 - m * m + 1e-5f);
  float sc = gw[o] * rs;
  float sel = (sc >= 0.f) ? ymax[i] : ymin[i];
  float v = (sel - m) * sc + gb[o];
  fout[i] = (v > 0.f) ? v : 0.2f * v;
}

// ---------------------------------------------------------------------------
extern "C" void kernel_launch(void* const* d_in, const int* in_sizes, int n_in,
                              void* d_out, int out_size, void* d_ws, size_t ws_size,
                              hipStream_t stream) {
  (void)in_sizes; (void)n_in; (void)out_size; (void)ws_size;
  const float* x    = (const float*)d_in[0];
  const float* W_in = (const float*)d_in[1];
  const float* b_in = (const float*)d_in[2];
  const float* W1   = (const float*)d_in[3];
  const float* g1w  = (const float*)d_in[4];
  const float* g1b  = (const float*)d_in[5];
  const float* W2   = (const float*)d_in[6];
  const float* g2w  = (const float*)d_in[7];
  const float* g2b  = (const float*)d_in[8];
  const float* W3   = (const float*)d_in[9];
  const float* g3w  = (const float*)d_in[10];
  const float* g3b  = (const float*)d_in[11];
  const float* W4   = (const float*)d_in[12];
  const float* g4w  = (const float*)d_in[13];
  const float* g4b  = (const float*)d_in[14];

  float* ws = (float*)d_ws;
  size_t o_c40  = 0;                                         // float4-aligned
  size_t o_nrm  = o_c40  + (size_t)B * N0 * 4;
  size_t o_pl   = o_nrm  + (size_t)B * N0 * 3;
  size_t o_f0   = o_pl   + (size_t)B * N0;
  size_t o_f1   = o_f0   + (size_t)B * N0 * 8;
  size_t o_ctrY = o_f1   + (size_t)B * N0 * 32;
  size_t o_ymin = o_ctrY + (size_t)B * N0 * 32;
  size_t o_ymax = o_ymin + (size_t)B * N0 * 32;
  size_t o_knnA = o_ymax + (size_t)B * N0 * 32;              // int region
  size_t o_knnB = o_knnA + (size_t)B * N0 * KNB;             // int region
  size_t o_gst  = o_knnB + (size_t)B * NQ * KNB;
  size_t o_idx1 = o_gst  + 4 * B * 8;                        // int region
  size_t o_idx2 = o_idx1 + (size_t)B * NQ;                   // int region
  size_t o_c4q1 = o_idx2 + (size_t)B * NQ;                   // float4-aligned
  size_t o_c4q2 = o_c4q1 + (size_t)B * NQ * 4;               // float4-aligned
  size_t o_nq1  = o_c4q2 + (size_t)B * NQ * 4;
  size_t o_pq1  = o_nq1  + (size_t)B * NQ * 3;
  size_t o_f2   = o_pq1  + (size_t)B * NQ;
  size_t o_f3   = o_f2   + (size_t)B * NQ * 64;

  float4* c40  = (float4*)(ws + o_c40);
  float*  nrm  = ws + o_nrm;   float* pl   = ws + o_pl;
  float*  f0   = ws + o_f0;    float* f1   = ws + o_f1;
  float*  ctrY = ws + o_ctrY;  float* ymin = ws + o_ymin;  float* ymax = ws + o_ymax;
  int*    knnA = (int*)(ws + o_knnA);
  int*    knnB = (int*)(ws + o_knnB);
  float*  gst  = ws + o_gst;
  int*    idx1 = (int*)(ws + o_idx1);
  int*    idx2 = (int*)(ws + o_idx2);
  float4* c4q1 = (float4*)(ws + o_c4q1);
  float4* c4q2 = (float4*)(ws + o_c4q2);
  float*  nq1  = ws + o_nq1;   float* pq1  = ws + o_pq1;
  float*  f2   = ws + o_f2;    float* f3   = ws + o_f3;

  float* out  = (float*)d_out;
  float* cq2  = out;                                   // (B,NQ,3)
  float* fout = out + (size_t)B * NQ * 3;              // (B,NQ,128)
  float* nq2  = fout + (size_t)B * NQ * 128;           // (B,NQ,3)
  float* pq2  = nq2 + (size_t)B * NQ * 3;              // (B,NQ,1)

  hipMemsetAsync(gst, 0, 4 * B * 8 * sizeof(float), stream);

  // stage 0
  prep_kernel<<<(B * N0 + 255) / 256, 256, 0, stream>>>(x, W_in, b_in, c40, nrm, pl, f0);

  // mega1: fps1 || knn1 || ctry1   (deps: prep only)
  mega1_kernel<<<8 + 4096 + 2048, 512, 0, stream>>>(c40, nrm, pl, f0, W1,
                                                    idx1, c4q1, nq1, pq1, knnA, ctrY);
  // layer 1 finish
  edgeconv_kernel<8, 32><<<B * N0 / 4, 256, 0, stream>>>(f0, f0, knnA, W1, ctrY, nullptr,
                                                         ymin, ymax, gst + 0, N0, N0);
  gn_out_kernel<32><<<(B * N0 * 32 + 255) / 256, 256, 0, stream>>>(
      ymin, ymax, gst + 0, g1w, g1b, f1, B * N0 * 32, N0, 1.0f / (4096.0f * 16.0f * 8.0f));

  // mega2: fps2 || knn2 || knn3 || ctry2   (deps: mega1 + gn_out1)
  mega2_kernel<<<8 + 1024 + 1024 + 1024, 512, 0, stream>>>(
      c40, c4q1, nq1, pq1, f1, idx1, W2, idx2, c4q2, cq2, nq2, pq2, knnA, knnB, ctrY);
  // layer 2 finish
  edgeconv_kernel<32, 64><<<B * NQ / 4, 256, 0, stream>>>(f1, f1, knnA, W2, ctrY, idx1,
                                                          ymin, ymax, gst + B * 8, NQ, N0);
  gn_out_kernel<64><<<(B * NQ * 64 + 255) / 256, 256, 0, stream>>>(
      ymin, ymax, gst + B * 8, g2w, g2b, f2, B * NQ * 64, NQ, 1.0f / (1024.0f * 16.0f * 16.0f));

  // layer 3 (dense, queries == keys == selected points)
  ctry_kernel<64, 64><<<(B * NQ * 64 + 255) / 256, 256, 0, stream>>>(f2, W3, ctrY, B * NQ * 64);
  edgeconv_kernel<64, 64><<<B * NQ / 4, 256, 0, stream>>>(f2, f2, knnB, W3, ctrY, nullptr,
                                                          ymin, ymax, gst + 2 * B * 8, NQ, NQ);
  gn_out_kernel<64><<<(B * NQ * 64 + 255) / 256, 256, 0, stream>>>(
      ymin, ymax, gst + 2 * B * 8, g3w, g3b, f3, B * NQ * 64, NQ, 1.0f / (1024.0f * 16.0f * 16.0f));

  // mega3: knn4 || ctry4   (deps: mega2 + gn_out3)
  mega3_kernel<<<1024 + 2048, 512, 0, stream>>>(c4q1, c4q2, f3, idx2, W4, knnB, ctrY);
  // layer 4 finish
  edgeconv_kernel<64, 128><<<B * NQ / 4, 256, 0, stream>>>(f3, f3, knnB, W4, ctrY, idx2,
                                                           ymin, ymax, gst + 3 * B * 8, NQ, NQ);
  gn_out_kernel<128><<<(B * NQ * 128 + 255) / 256, 256, 0, stream>>>(
      ymin, ymax, gst + 3 * B * 8, g4w, g4b, fout, B * NQ * 128, NQ, 1.0f / (1024.0f * 16.0f * 32.0f));
}

// Round 6
// 1497.779 us; speedup vs baseline: 1.8728x; 1.2483x over previous
//
#include <hip/hip_runtime.h>
#include <cstdint>

static constexpr int B   = 8;
static constexpr int N0  = 4096;
static constexpr int NQ  = 1024;
static constexpr int KNB = 16;

// ---------------------------------------------------------------------------
// DPP wave reductions (no DS ops). row_shr 1,2,4,8 + row_bcast15/31;
// full-wave result in lane 63. update_dpp(old=x, src=x): invalid lanes keep x.
// ---------------------------------------------------------------------------
__device__ __forceinline__ float wave_min_bcast_f32(float x) {
#define STEP_(ctrl)                                                                     \
  {                                                                                     \
    int t_ = __builtin_amdgcn_update_dpp(__float_as_int(x), __float_as_int(x), ctrl,    \
                                         0xf, 0xf, false);                              \
    x = fminf(x, __int_as_float(t_));                                                   \
  }
  STEP_(0x111) STEP_(0x112) STEP_(0x114) STEP_(0x118) STEP_(0x142) STEP_(0x143)
#undef STEP_
  return __int_as_float(__builtin_amdgcn_readlane(__float_as_int(x), 63));
}

__device__ __forceinline__ unsigned wave_min_bcast_u32(unsigned x) {
#define STEP_(ctrl)                                                                     \
  {                                                                                     \
    unsigned t_ = (unsigned)__builtin_amdgcn_update_dpp((int)x, (int)x, ctrl,           \
                                                        0xf, 0xf, false);               \
    x = (t_ < x) ? t_ : x;                                                              \
  }
  STEP_(0x111) STEP_(0x112) STEP_(0x114) STEP_(0x118) STEP_(0x142) STEP_(0x143)
#undef STEP_
  return (unsigned)__builtin_amdgcn_readlane((int)x, 63);
}

// u64 wave max; result valid in LANE 63 only. No readlane/ballot — pure VALU.
__device__ __forceinline__ unsigned long long wave_max_u64_l63(unsigned long long k) {
#define STEPU_(ctrl)                                                                    \
  {                                                                                     \
    unsigned lo_ = (unsigned)k, hi_ = (unsigned)(k >> 32);                              \
    unsigned plo_ = (unsigned)__builtin_amdgcn_update_dpp((int)lo_, (int)lo_, ctrl,     \
                                                          0xf, 0xf, false);             \
    unsigned phi_ = (unsigned)__builtin_amdgcn_update_dpp((int)hi_, (int)hi_, ctrl,     \
                                                          0xf, 0xf, false);             \
    unsigned long long pk_ = ((unsigned long long)phi_ << 32) | plo_;                   \
    if (pk_ > k) k = pk_;                                                               \
  }
  STEPU_(0x111) STEPU_(0x112) STEPU_(0x114) STEPU_(0x118) STEPU_(0x142) STEPU_(0x143)
#undef STEPU_
  return k;
}

// ---------------------------------------------------------------------------
// prep: split x; write packed c4 = {x,y,z,|c|^2}, normal, plane, f0
// ---------------------------------------------------------------------------
__global__ void prep_kernel(const float* __restrict__ x,
                            const float* __restrict__ W_in,
                            const float* __restrict__ b_in,
                            float4* __restrict__ c4, float* __restrict__ nrm,
                            float* __restrict__ pl, float* __restrict__ f0) {
  int i = blockIdx.x * 256 + threadIdx.x;
  if (i >= B * N0) return;
  const float* xp = x + (size_t)i * 7;
  float cx = xp[0], cy = xp[1], cz = xp[2];
  // tie-sensitive (feeds kNN distance): exact fp32, ref association order
  float kk = __fadd_rn(__fadd_rn(__fmul_rn(cx, cx), __fmul_rn(cy, cy)), __fmul_rn(cz, cz));
  c4[i] = make_float4(cx, cy, cz, kk);
  nrm[i * 3 + 0] = xp[3]; nrm[i * 3 + 1] = xp[4]; nrm[i * 3 + 2] = xp[5];
  pl[i] = xp[6];
#pragma unroll
  for (int o = 0; o < 8; o++) {
    f0[(size_t)i * 8 + o] = cx * W_in[o * 3 + 0] + cy * W_in[o * 3 + 1] + cz * W_in[o * 3 + 2] + b_in[o];
  }
}

// ---------------------------------------------------------------------------
// kNN body: wave per query (bq). Lane owns M=Nk/64 candidates.
// 16 rounds of DPP wave argmin (tie -> smaller index == stable top_k).
// d2 = ((|q|^2 - 2*dot) + |k|^2), exact fp32 non-fused like the reference.
// ---------------------------------------------------------------------------
template <int M>
__device__ __forceinline__ void knn_body(int bq, int lane,
                                         const float4* __restrict__ q4,
                                         const float4* __restrict__ k4,
                                         int Q, int Nk, int* __restrict__ out) {
  int b = bq / Q;
  float4 q = q4[bq];
  const float4* kb = k4 + (size_t)b * Nk;
  float d[M];
#pragma unroll
  for (int i = 0; i < M; i++) {
    float4 kp = kb[i * 64 + lane];
    float dot = __fadd_rn(__fadd_rn(__fmul_rn(q.x, kp.x), __fmul_rn(q.y, kp.y)),
                          __fmul_rn(q.z, kp.z));
    d[i] = __fadd_rn(__fsub_rn(q.w, __fmul_rn(2.0f, dot)), kp.w);
  }
  unsigned long long mask = 0ull;
  float lv = 3.0e38f; int li = 0;
#pragma unroll
  for (int i = 0; i < M; i++) { if (d[i] < lv) { lv = d[i]; li = i; } }
  int mynb = 0;
  for (int r = 0; r < KNB; r++) {
    int n = li * 64 + lane;
    float wmin = wave_min_bcast_f32(lv);
    unsigned ci = (lv == wmin) ? (unsigned)n : 0xFFFFFFFFu;
    int wn = (int)wave_min_bcast_u32(ci);
    if (lane == r) mynb = wn;
    if (lane == (wn & 63)) {  // owner lane: mark + rescan
      mask |= 1ull << (wn >> 6);
      lv = 3.0e38f; li = 0;
#pragma unroll
      for (int i = 0; i < M; i++) {
        bool dead = (mask >> i) & 1ull;
        float dv = dead ? 3.0e38f : d[i];
        if (dv < lv) { lv = dv; li = i; }
      }
    }
  }
  if (lane < KNB) out[(size_t)bq * KNB + lane] = mynb;
}

// ---------------------------------------------------------------------------
// ctrY body: ctrY[b,q,o] = sum_c fq_row[c] * W[o, CF+c]; optional row
// indirection (fq_row = fq[b*Nsrc + ridx[bq]]) replaces the f-gather.
// ---------------------------------------------------------------------------
template <int CF, int CO>
__device__ __forceinline__ void ctry_body(int i, int total, const float* __restrict__ fq,
                                          const float* __restrict__ W,
                                          float* __restrict__ ctrY,
                                          const int* __restrict__ ridx, int Q, int Nsrc) {
  if (i >= total) return;
  int o = i % CO, bq = i / CO;
  const float* fp;
  if (ridx) {
    int b = bq / Q;
    fp = fq + ((size_t)b * Nsrc + ridx[bq]) * CF;
  } else {
    fp = fq + (size_t)bq * CF;
  }
  const float* wp = W + (size_t)o * (2 * CF) + CF;
  float acc = 0.f;
#pragma unroll
  for (int c = 0; c < CF; c++) acc = fmaf(fp[c], wp[c], acc);
  ctrY[i] = acc;
}

// ---------------------------------------------------------------------------
// FPS v5: BLK=256 (4 waves), one block per batch, selects NQ=1024 points.
// SCALAR-FREE tail: key k=(dist_bits<<12)|(4095-bi) is DPP-u64-maxed directly
// (winner unique since indices distinct); lane 63 writes the wave slot;
// ONE barrier; cross-wave reduce = 2x ds_read_b128 broadcast + 3 u64 maxes;
// winner coords via same-address (broadcast) LDS reads sxy[win]/sz[win].
// No readlane / ballot / ffs anywhere in the loop. Winners buffered in
// registers (thread tid keeps t==tid+{0,256,512,768}), flushed after loop.
// u64 max == (max dist, tie -> min index) exactly (dists >= 0), matching
// jnp.argmax first-occurrence semantics.
// ---------------------------------------------------------------------------
template <int NPTS>
__device__ __forceinline__ void fps_body(const float4* __restrict__ cb, int* w) {
  constexpr int BLK = 256;
  constexpr int M = NPTS / BLK;
  constexpr int NW = BLK / 64;  // 4
  __shared__ __align__(16) float2 sxy[NPTS];
  __shared__ float szz[NPTS];
  __shared__ __align__(16) unsigned long long skey[2][NW];
  const int tid = threadIdx.x;
  const int wid = tid >> 6, lane = tid & 63;
  float cx[M], cy[M], cz[M], dist[M];
#pragma unroll
  for (int i = 0; i < M; i++) {
    float4 p = cb[tid * M + i];
    cx[i] = p.x; cy[i] = p.y; cz[i] = p.z;
    dist[i] = 3.4e38f;
    sxy[tid * M + i] = make_float2(p.x, p.y);
    szz[tid * M + i] = p.z;
  }
  w[0] = w[1] = w[2] = w[3] = 0;
  float4 p0 = cb[0];
  float px = p0.x, py = p0.y, pz = p0.z;
  __syncthreads();
  for (int t = 1; t < NQ; t++) {
    float bv = -1.f; int bi = 0;
#pragma unroll
    for (int i = 0; i < M; i++) {
      float dx = __fsub_rn(cx[i], px), dy = __fsub_rn(cy[i], py), dz = __fsub_rn(cz[i], pz);
      float d = __fadd_rn(__fadd_rn(__fmul_rn(dx, dx), __fmul_rn(dy, dy)), __fmul_rn(dz, dz));
      float dd = dist[i]; dd = (d < dd) ? d : dd; dist[i] = dd;
      if (dd > bv) { bv = dd; bi = tid * M + i; }
    }
    unsigned long long k =
        ((unsigned long long)__float_as_uint(bv) << 12) | (unsigned)(4095 - bi);
    k = wave_max_u64_l63(k);
    int p = t & 1;
    if (lane == 63) skey[p][wid] = k;
    __syncthreads();
    ulonglong2 ab = *(const ulonglong2*)&skey[p][0];
    ulonglong2 cd = *(const ulonglong2*)&skey[p][2];
    unsigned long long m0 = (ab.x > ab.y) ? ab.x : ab.y;
    unsigned long long m1 = (cd.x > cd.y) ? cd.x : cd.y;
    unsigned long long mk = (m0 > m1) ? m0 : m1;
    int win = 4095 - (int)(mk & 0xFFFull);
    float2 pxy = sxy[win];
    px = pxy.x; py = pxy.y; pz = szz[win];
    if (t == tid) w[0] = win;
    if (t == tid + 256) w[1] = win;
    if (t == tid + 512) w[2] = win;
    if (t == tid + 768) w[3] = win;
  }
}

// ---------------------------------------------------------------------------
// mega1: blocks [0,8) fps1 (+ coord/nrm/pl gather tail); [8,8200) knn1;
// rest ctry1. All roles depend only on prep outputs; no inter-block deps.
// ---------------------------------------------------------------------------
__global__ __launch_bounds__(256, 2) void mega1_kernel(
    const float4* __restrict__ c40, const float* __restrict__ nrm,
    const float* __restrict__ pl, const float* __restrict__ f0,
    const float* __restrict__ W1, int* __restrict__ idx1,
    float4* __restrict__ c4q1, float* __restrict__ nq1, float* __restrict__ pq1,
    int* __restrict__ knn1, float* __restrict__ ctrY1) {
  int blk = blockIdx.x;
  if (blk < 8) {
    const int b = blk, tid = threadIdx.x;
    const float4* cb = c40 + (size_t)b * N0;
    int w[4];
    fps_body<N0>(cb, w);
    int* idxb = idx1 + (size_t)b * NQ;
#pragma unroll
    for (int u = 0; u < 4; u++) {
      int r = tid + u * 256;
      int s = (u == 0 && tid == 0) ? 0 : w[u];
      idxb[r] = s;
      c4q1[(size_t)b * NQ + r] = cb[s];
      const float* np = nrm + ((size_t)b * N0 + s) * 3;
      float* ndp = nq1 + ((size_t)b * NQ + r) * 3;
      ndp[0] = np[0]; ndp[1] = np[1]; ndp[2] = np[2];
      pq1[(size_t)b * NQ + r] = pl[(size_t)b * N0 + s];
    }
  } else if (blk < 8 + 8192) {
    int bq = (blk - 8) * 4 + (threadIdx.x >> 6);
    knn_body<64>(bq, threadIdx.x & 63, c40, c40, N0, N0, knn1);
  } else {
    int i = (blk - (8 + 8192)) * 256 + threadIdx.x;
    ctry_body<8, 32>(i, B * N0 * 32, f0, W1, ctrY1, nullptr, 0, 0);
  }
}

// ---------------------------------------------------------------------------
// mega2: blocks [0,8) fps2 (+ gather tail -> c4q2, d_out coords/normal/plane);
// [8,2056) knn2 (c4q1 vs c40); [2056,4104) knn3 (c4q1 vs c4q1); rest ctry2.
// All roles depend only on {mega1, gn_out1} outputs.
// ---------------------------------------------------------------------------
__global__ __launch_bounds__(256, 2) void mega2_kernel(
    const float4* __restrict__ c40, const float4* __restrict__ c4q1,
    const float* __restrict__ nq1, const float* __restrict__ pq1,
    const float* __restrict__ f1, const int* __restrict__ idx1,
    const float* __restrict__ W2, int* __restrict__ idx2,
    float4* __restrict__ c4q2, float* __restrict__ cq2out,
    float* __restrict__ nq2out, float* __restrict__ pq2out,
    int* __restrict__ knn2, int* __restrict__ knn3, float* __restrict__ ctrY2) {
  int blk = blockIdx.x;
  if (blk < 8) {
    const int b = blk, tid = threadIdx.x;
    const float4* cqb = c4q1 + (size_t)b * NQ;
    int w[4];
    fps_body<NQ>(cqb, w);
    int* idxb = idx2 + (size_t)b * NQ;
#pragma unroll
    for (int u = 0; u < 4; u++) {
      int r = tid + u * 256;
      int s = (u == 0 && tid == 0) ? 0 : w[u];
      idxb[r] = s;
      float4 c = cqb[s];
      c4q2[(size_t)b * NQ + r] = c;
      float* cd = cq2out + ((size_t)b * NQ + r) * 3;
      cd[0] = c.x; cd[1] = c.y; cd[2] = c.z;
      const float* np = nq1 + ((size_t)b * NQ + s) * 3;
      float* ndp = nq2out + ((size_t)b * NQ + r) * 3;
      ndp[0] = np[0]; ndp[1] = np[1]; ndp[2] = np[2];
      pq2out[(size_t)b * NQ + r] = pq1[(size_t)b * NQ + s];
    }
  } else if (blk < 8 + 2048) {
    int bq = (blk - 8) * 4 + (threadIdx.x >> 6);
    knn_body<64>(bq, threadIdx.x & 63, c4q1, c40, NQ, N0, knn2);
  } else if (blk < 8 + 4096) {
    int bq = (blk - (8 + 2048)) * 4 + (threadIdx.x >> 6);
    knn_body<16>(bq, threadIdx.x & 63, c4q1, c4q1, NQ, NQ, knn3);
  } else {
    int i = (blk - (8 + 4096)) * 256 + threadIdx.x;
    ctry_body<32, 64>(i, B * NQ * 64, f1, W2, ctrY2, idx1, NQ, N0);
  }
}

// ---------------------------------------------------------------------------
// mega3: blocks [0,2048) knn4 (c4q2 vs c4q1); rest ctry4 (f3 rows via idx2).
// ---------------------------------------------------------------------------
__global__ __launch_bounds__(256, 4) void mega3_kernel(
    const float4* __restrict__ c4q1, const float4* __restrict__ c4q2,
    const float* __restrict__ f3, const int* __restrict__ idx2,
    const float* __restrict__ W4, int* __restrict__ knn4, float* __restrict__ ctrY4) {
  int blk = blockIdx.x;
  if (blk < 2048) {
    int bq = blk * 4 + (threadIdx.x >> 6);
    knn_body<16>(bq, threadIdx.x & 63, c4q2, c4q1, NQ, NQ, knn4);
  } else {
    int i = (blk - 2048) * 256 + threadIdx.x;
    ctry_body<64, 128>(i, B * NQ * 128, f3, W4, ctrY4, idx2, NQ, NQ);
  }
}

// ---------------------------------------------------------------------------
// standalone ctry (layer 3, dense)
// ---------------------------------------------------------------------------
template <int CF, int CO>
__global__ void ctry_kernel(const float* __restrict__ fq, const float* __restrict__ W,
                            float* __restrict__ ctrY, int total) {
  int i = blockIdx.x * 256 + threadIdx.x;
  ctry_body<CF, CO>(i, total, fq, W, ctrY, nullptr, 0, 0);
}

// ---------------------------------------------------------------------------
// edge-conv pass A: wave per (b,q); lane = g*16+k. y = Wl*(nb-ctr) + ctrY;
// min/max over k per channel; per-(b,group) sum/sumsq. Optional ridx:
// center row = fq[b*Nk + ridx[bq]] (replaces f-gather).
// ---------------------------------------------------------------------------
template <int CF, int CO>
__global__ __launch_bounds__(256) void edgeconv_kernel(
    const float* __restrict__ fq, const float* __restrict__ fk,
    const int* __restrict__ knn, const float* __restrict__ Wfull,
    const float* __restrict__ ctrY, const int* __restrict__ ridx,
    float* __restrict__ ymin, float* __restrict__ ymax,
    float* __restrict__ gstats, int Q, int Nk) {
  constexpr int J = CO / 4;
  constexpr int SEC = J * CF + 8;
  __shared__ float Wl[4 * SEC];
  __shared__ float sstat[8];
  for (int t = threadIdx.x; t < CO * CF; t += 256) {
    int o = t / CF, c = t % CF;
    Wl[(o / J) * SEC + (o % J) * CF + c] = Wfull[(size_t)o * (2 * CF) + c];
  }
  if (threadIdx.x < 8) sstat[threadIdx.x] = 0.0f;
  __syncthreads();
  const int wid = threadIdx.x >> 6, lane = threadIdx.x & 63;
  const int bq = blockIdx.x * 4 + wid;
  const int b = bq / Q;
  const int g = lane >> 4, k = lane & 15;
  const int ni = knn[(size_t)bq * KNB + k];
  const float* nbp = fk + (size_t)(b * Nk + ni) * CF;
  const float* cp = ridx ? fq + ((size_t)b * Nk + ridx[bq]) * CF
                         : fq + (size_t)bq * CF;
  float acc[J];
#pragma unroll
  for (int j = 0; j < J; j++) acc[j] = 0.0f;
  const float* wg = &Wl[g * SEC];
#pragma unroll
  for (int c = 0; c < CF; c += 4) {
    float4 nb4 = *(const float4*)(nbp + c);
    float4 c4  = *(const float4*)(cp + c);
    float e0 = nb4.x - c4.x, e1 = nb4.y - c4.y, e2 = nb4.z - c4.z, e3 = nb4.w - c4.w;
#pragma unroll
    for (int j = 0; j < J; j++) {
      float4 w4 = *(const float4*)(wg + j * CF + c);
      acc[j] = fmaf(e0, w4.x, acc[j]);
      acc[j] = fmaf(e1, w4.y, acc[j]);
      acc[j] = fmaf(e2, w4.z, acc[j]);
      acc[j] = fmaf(e3, w4.w, acc[j]);
    }
  }
  float s = 0.f, s2 = 0.f;
  const float* cyp = ctrY + (size_t)bq * CO + g * J;
#pragma unroll
  for (int j = 0; j < J; j++) {
    float y = acc[j] + cyp[j];
    acc[j] = y;            // acc becomes running max
    s += y; s2 = fmaf(y, y, s2);
  }
  float mn[J];
#pragma unroll
  for (int j = 0; j < J; j++) mn[j] = acc[j];
#pragma unroll
  for (int m = 1; m < 16; m <<= 1) {  // reduce over the 16 k-lanes
#pragma unroll
    for (int j = 0; j < J; j++) {
      float a = __shfl_xor(acc[j], m); if (a > acc[j]) acc[j] = a;
      float c2 = __shfl_xor(mn[j], m); if (c2 < mn[j]) mn[j] = c2;
    }
    s  += __shfl_xor(s, m);
    s2 += __shfl_xor(s2, m);
  }
  if (k == 0) {
    float* mnp = ymin + (size_t)bq * CO + g * J;
    float* mxp = ymax + (size_t)bq * CO + g * J;
#pragma unroll
    for (int j = 0; j < J; j++) { mnp[j] = mn[j]; mxp[j] = acc[j]; }
    atomicAdd(&sstat[g], s);
    atomicAdd(&sstat[4 + g], s2);
  }
  __syncthreads();
  if (threadIdx.x < 8) atomicAdd(&gstats[b * 8 + threadIdx.x], sstat[threadIdx.x]);
}

// ---------------------------------------------------------------------------
// pass B (gn_final fused): f = lrelu((sel - m)*gw*rs + gb),
// sel = max over K if scale>=0 else min (monotone-commute, exact).
// ---------------------------------------------------------------------------
template <int CO>
__global__ void gn_out_kernel(const float* __restrict__ ymin, const float* __restrict__ ymax,
                              const float* __restrict__ gstats, const float* __restrict__ gw,
                              const float* __restrict__ gb, float* __restrict__ fout,
                              int total, int Q, float inv_cnt) {
  int i = blockIdx.x * 256 + threadIdx.x;
  if (i >= total) return;
  constexpr int J = CO / 4;
  int o = i % CO; int bq = i / CO; int b = bq / Q;
  int g = o / J;
  float m  = gstats[b * 8 + g] * inv_cnt;
  float s2 = gstats[b * 8 + 4 + g] * inv_cnt;
  float rs = rsqrtf(s2 - m * m + 1e-5f);
  float sc = gw[o] * rs;
  float sel = (sc >= 0.f) ? ymax[i] : ymin[i];
  float v = (sel - m) * sc + gb[o];
  fout[i] = (v > 0.f) ? v : 0.2f * v;
}

// ---------------------------------------------------------------------------
extern "C" void kernel_launch(void* const* d_in, const int* in_sizes, int n_in,
                              void* d_out, int out_size, void* d_ws, size_t ws_size,
                              hipStream_t stream) {
  (void)in_sizes; (void)n_in; (void)out_size; (void)ws_size;
  const float* x    = (const float*)d_in[0];
  const float* W_in = (const float*)d_in[1];
  const float* b_in = (const float*)d_in[2];
  const float* W1   = (const float*)d_in[3];
  const float* g1w  = (const float*)d_in[4];
  const float* g1b  = (const float*)d_in[5];
  const float* W2   = (const float*)d_in[6];
  const float* g2w  = (const float*)d_in[7];
  const float* g2b  = (const float*)d_in[8];
  const float* W3   = (const float*)d_in[9];
  const float* g3w  = (const float*)d_in[10];
  const float* g3b  = (const float*)d_in[11];
  const float* W4   = (const float*)d_in[12];
  const float* g4w  = (const float*)d_in[13];
  const float* g4b  = (const float*)d_in[14];

  float* ws = (float*)d_ws;
  size_t o_c40  = 0;                                         // float4-aligned
  size_t o_nrm  = o_c40  + (size_t)B * N0 * 4;
  size_t o_pl   = o_nrm  + (size_t)B * N0 * 3;
  size_t o_f0   = o_pl   + (size_t)B * N0;
  size_t o_f1   = o_f0   + (size_t)B * N0 * 8;
  size_t o_ctrY = o_f1   + (size_t)B * N0 * 32;
  size_t o_ymin = o_ctrY + (size_t)B * N0 * 32;
  size_t o_ymax = o_ymin + (size_t)B * N0 * 32;
  size_t o_knnA = o_ymax + (size_t)B * N0 * 32;              // int region
  size_t o_knnB = o_knnA + (size_t)B * N0 * KNB;             // int region
  size_t o_gst  = o_knnB + (size_t)B * NQ * KNB;
  size_t o_idx1 = o_gst  + 4 * B * 8;                        // int region
  size_t o_idx2 = o_idx1 + (size_t)B * NQ;                   // int region
  size_t o_c4q1 = o_idx2 + (size_t)B * NQ;                   // float4-aligned
  size_t o_c4q2 = o_c4q1 + (size_t)B * NQ * 4;               // float4-aligned
  size_t o_nq1  = o_c4q2 + (size_t)B * NQ * 4;
  size_t o_pq1  = o_nq1  + (size_t)B * NQ * 3;
  size_t o_f2   = o_pq1  + (size_t)B * NQ;
  size_t o_f3   = o_f2   + (size_t)B * NQ * 64;

  float4* c40  = (float4*)(ws + o_c40);
  float*  nrm  = ws + o_nrm;   float* pl   = ws + o_pl;
  float*  f0   = ws + o_f0;    float* f1   = ws + o_f1;
  float*  ctrY = ws + o_ctrY;  float* ymin = ws + o_ymin;  float* ymax = ws + o_ymax;
  int*    knnA = (int*)(ws + o_knnA);
  int*    knnB = (int*)(ws + o_knnB);
  float*  gst  = ws + o_gst;
  int*    idx1 = (int*)(ws + o_idx1);
  int*    idx2 = (int*)(ws + o_idx2);
  float4* c4q1 = (float4*)(ws + o_c4q1);
  float4* c4q2 = (float4*)(ws + o_c4q2);
  float*  nq1  = ws + o_nq1;   float* pq1  = ws + o_pq1;
  float*  f2   = ws + o_f2;    float* f3   = ws + o_f3;

  float* out  = (float*)d_out;
  float* cq2  = out;                                   // (B,NQ,3)
  float* fout = out + (size_t)B * NQ * 3;              // (B,NQ,128)
  float* nq2  = fout + (size_t)B * NQ * 128;           // (B,NQ,3)
  float* pq2  = nq2 + (size_t)B * NQ * 3;              // (B,NQ,1)

  hipMemsetAsync(gst, 0, 4 * B * 8 * sizeof(float), stream);

  // stage 0
  prep_kernel<<<(B * N0 + 255) / 256, 256, 0, stream>>>(x, W_in, b_in, c40, nrm, pl, f0);

  // mega1: fps1 || knn1 || ctry1   (deps: prep only)
  mega1_kernel<<<8 + 8192 + 4096, 256, 0, stream>>>(c40, nrm, pl, f0, W1,
                                                    idx1, c4q1, nq1, pq1, knnA, ctrY);
  // layer 1 finish
  edgeconv_kernel<8, 32><<<B * N0 / 4, 256, 0, stream>>>(f0, f0, knnA, W1, ctrY, nullptr,
                                                         ymin, ymax, gst + 0, N0, N0);
  gn_out_kernel<32><<<(B * N0 * 32 + 255) / 256, 256, 0, stream>>>(
      ymin, ymax, gst + 0, g1w, g1b, f1, B * N0 * 32, N0, 1.0f / (4096.0f * 16.0f * 8.0f));

  // mega2: fps2 || knn2 || knn3 || ctry2   (deps: mega1 + gn_out1)
  mega2_kernel<<<8 + 2048 + 2048 + 2048, 256, 0, stream>>>(
      c40, c4q1, nq1, pq1, f1, idx1, W2, idx2, c4q2, cq2, nq2, pq2, knnA, knnB, ctrY);
  // layer 2 finish
  edgeconv_kernel<32, 64><<<B * NQ / 4, 256, 0, stream>>>(f1, f1, knnA, W2, ctrY, idx1,
                                                          ymin, ymax, gst + B * 8, NQ, N0);
  gn_out_kernel<64><<<(B * NQ * 64 + 255) / 256, 256, 0, stream>>>(
      ymin, ymax, gst + B * 8, g2w, g2b, f2, B * NQ * 64, NQ, 1.0f / (1024.0f * 16.0f * 16.0f));

  // layer 3 (dense, queries == keys == selected points)
  ctry_kernel<64, 64><<<(B * NQ * 64 + 255) / 256, 256, 0, stream>>>(f2, W3, ctrY, B * NQ * 64);
  edgeconv_kernel<64, 64><<<B * NQ / 4, 256, 0, stream>>>(f2, f2, knnB, W3, ctrY, nullptr,
                                                          ymin, ymax, gst + 2 * B * 8, NQ, NQ);
  gn_out_kernel<64><<<(B * NQ * 64 + 255) / 256, 256, 0, stream>>>(
      ymin, ymax, gst + 2 * B * 8, g3w, g3b, f3, B * NQ * 64, NQ, 1.0f / (1024.0f * 16.0f * 16.0f));

  // mega3: knn4 || ctry4   (deps: mega2 + gn_out3)
  mega3_kernel<<<2048 + 4096, 256, 0, stream>>>(c4q1, c4q2, f3, idx2, W4, knnB, ctrY);
  // layer 4 finish
  edgeconv_kernel<64, 128><<<B * NQ / 4, 256, 0, stream>>>(f3, f3, knnB, W4, ctrY, idx2,
                                                           ymin, ymax, gst + 3 * B * 8, NQ, NQ);
  gn_out_kernel<128><<<(B * NQ * 128 + 255) / 256, 256, 0, stream>>>(
      ymin, ymax, gst + 3 * B * 8, g4w, g4b, fout, B * NQ * 128, NQ, 1.0f / (1024.0f * 16.0f * 32.0f));
}